// Round 6
// baseline (461.744 us; speedup 1.0000x reference)
//
#include <hip/hip_runtime.h>
#include <math.h>

// FlashMultiHeadAttention: B=32 S=500 H=1024 NH=16 HD=64, rope + rel-pos-bias + key-pad mask.
// Pipeline: [mask->bytes] [gather-list scan] [rope table] [f32->bf16 cvt]
//           [QKV proj GEMM 256x256 8-wave 2-phase] [rope Q] [rope+gather+swizzle K tiles]
//           [gather+transpose+swizzle V tiles] [flash attn: masked-k compressed,
//            swapped QK^T, in-register softmax, prefetch pipeline] [out proj GEMM]

typedef unsigned short u16;
typedef unsigned int   u32;
typedef unsigned char  u8;
using bf16x8 = __attribute__((ext_vector_type(8))) short;
using f32x4  = __attribute__((ext_vector_type(4))) float;
using f32x2  = __attribute__((ext_vector_type(2))) float;
using u16x4  = __attribute__((ext_vector_type(4))) unsigned short;

#define DEV __device__ __forceinline__

#if __has_builtin(__builtin_amdgcn_exp2f)
#define EXP2(x) __builtin_amdgcn_exp2f(x)
#else
#define EXP2(x) exp2f(x)
#endif

DEV u16 f2bf(float f) {                 // RNE f32 -> bf16
  union { float f; u32 u; } c; c.f = f;
  u32 u = c.u;
  return (u16)((u + 0x7FFFu + ((u >> 16) & 1u)) >> 16);
}
DEV float bf2f(u16 h) {
  union { u32 u; float f; } c; c.u = ((u32)h) << 16;
  return c.f;
}
DEV u32 packbf(float a, float b) {      // half-up rounding, packed pair
  union { float f; u32 u; } x, y; x.f = a; y.f = b;
  return ((x.u + 0x8000u) >> 16) | ((y.u + 0x8000u) & 0xFFFF0000u);
}

// async global->LDS, 16B/lane; LDS dest = wave-uniform base + lane*16 (linear).
DEV void async16(void* l, const void* g) {
  __builtin_amdgcn_global_load_lds(
      (__attribute__((address_space(1))) unsigned int*)g,
      (__attribute__((address_space(3))) unsigned int*)l, 16, 0, 0);
}

// ---------------- mask prep: detect bool storage (i32/f32/u8), emit bytes ----------------
__global__ __launch_bounds__(256) void mask_prep(const void* __restrict__ mraw,
                                                 u8* __restrict__ maskb) {
  __shared__ int bad_i32, bad_f32;
  if (threadIdx.x == 0) { bad_i32 = 0; bad_f32 = 0; }
  __syncthreads();
  const u32* w = (const u32*)mraw;
  int li = 0, lf = 0;
  for (int g = threadIdx.x; g < 4000; g += 256) {
    u32 v = w[g];
    li |= !(v == 0u || v == 1u);
    lf |= !(v == 0u || v == 0x3F800000u);
  }
  if (li) atomicOr(&bad_i32, 1);
  if (lf) atomicOr(&bad_f32, 1);
  __syncthreads();
  int mode = (!bad_i32) ? 0 : ((!bad_f32) ? 1 : 2);   // 0=int32, 1=float32, 2=uint8
  for (int i = threadIdx.x; i < 16000; i += 256) {
    int v;
    if (mode == 0)      v = ((const int*)mraw)[i] != 0;
    else if (mode == 1) v = (((const float*)mraw)[i] != 0.0f);
    else                v = ((const u8*)mraw)[i] != 0;
    maskb[i] = (u8)v;
  }
}

// ---------------- per-batch gather list: karr[b][512] = kept token or 0xFFFF ----------------
__global__ __launch_bounds__(512) void build_gather(const u8* __restrict__ maskb,
                                                    u16* __restrict__ karr,
                                                    int* __restrict__ kept) {
  const int b = blockIdx.x;
  const int t = threadIdx.x;
  const int lane = t & 63, wave = t >> 6;
  __shared__ int wbase[8];
  __shared__ int wpop[8];
  int v = (t < 500) ? (int)maskb[b * 500 + t] : 0;
  unsigned long long bal = __ballot(v != 0);
  karr[b * 512 + t] = 0xFFFF;
  if (lane == 0) wpop[wave] = __popcll(bal);
  __syncthreads();
  if (t == 0) {
    int s = 0;
    for (int w = 0; w < 8; ++w) { wbase[w] = s; s += wpop[w]; }
    kept[b] = s;
  }
  __syncthreads();
  if (v) {
    int rank = wbase[wave] + __popcll(bal & ((1ull << lane) - 1ull));
    karr[b * 512 + rank] = (u16)t;
  }
}

// ---------------- rope cos/sin table: tab[(s*32+j)*2] = cos, +1 = sin ----------------
__global__ __launch_bounds__(256) void rope_table(float* __restrict__ tab) {
  int idx = blockIdx.x * 256 + threadIdx.x;
  if (idx >= 16000) return;
  int s = idx >> 5, j = idx & 31;
  float ang = (float)s * exp2f(-(float)j * 0.41524100f);  // 10000^(-j/32)
  float sn, cs;
  sincosf(ang, &sn, &cs);
  tab[idx * 2] = cs;
  tab[idx * 2 + 1] = sn;
}

// ---------------- f32 -> bf16 convert (vectorized) ----------------
__global__ __launch_bounds__(256) void cvt_f32_bf16(const float* __restrict__ src,
                                                    u16* __restrict__ dst, int n4) {
  int i = blockIdx.x * 256 + threadIdx.x;
  int stride = gridDim.x * 256;
  for (; i < n4; i += stride) {
    f32x4 f = *(const f32x4*)(src + (size_t)i * 4);
    u16x4 o;
    o[0] = f2bf(f[0]); o[1] = f2bf(f[1]); o[2] = f2bf(f[2]); o[3] = f2bf(f[3]);
    *(u16x4*)(dst + (size_t)i * 4) = o;
  }
}

// ---------------- GEMM: C[m][n] = sum_k A[m][k]*Bw[n][k] + bias[n] ----------------
// 256x256 tile, BK=32, 512 threads / 8 waves (2x4), per-wave 128x64 (8x4 frags),
// double-buffered LDS (64KB), 2-phase prefetch. Grid (ceil(M/256), N/256) ~ 1 block/CU.
template <bool OUT_BF16>
__global__ __launch_bounds__(512) void gemm_bt(const u16* __restrict__ A,
                                               const u16* __restrict__ Bw,
                                               const float* __restrict__ bias,
                                               void* __restrict__ Cout, int M) {
  const int m0 = blockIdx.x * 256;
  const int n0 = blockIdx.y * 256;
  const int tid = threadIdx.x;
  const int wave = tid >> 6;
  const int wr = wave >> 2, wc = wave & 3;
  const int fr = tid & 15, fo = (tid >> 4) & 3;

  __shared__ __attribute__((aligned(16))) u16 As[2][256 * 32];   // 16KB each
  __shared__ __attribute__((aligned(16))) u16 Bs[2][256 * 32];

  f32x4 acc[8][4];
#pragma unroll
  for (int mi = 0; mi < 8; ++mi)
#pragma unroll
    for (int ni = 0; ni < 4; ++ni)
#pragma unroll
      for (int j = 0; j < 4; ++j) acc[mi][ni][j] = 0.f;

  // prologue: stage kt=0 into buf0
#pragma unroll
  for (int i = 0; i < 2; ++i) {
    int slot = i * 512 + tid;            // 1024 slots of 16B per matrix tile
    int row = slot >> 2, seg = slot & 3;
    int ar = min(m0 + row, M - 1);
    async16(&As[0][slot * 8], A + (size_t)ar * 1024 + seg * 8);
    async16(&Bs[0][slot * 8], Bw + (size_t)(n0 + row) * 1024 + seg * 8);
  }
  __syncthreads();

  for (int kt = 0; kt < 32; ++kt) {
    const int cur = kt & 1;
    if (kt + 1 < 32) {                   // issue next-tile loads before compute
#pragma unroll
      for (int i = 0; i < 2; ++i) {
        int slot = i * 512 + tid;
        int row = slot >> 2, seg = slot & 3;
        int ar = min(m0 + row, M - 1);
        async16(&As[cur ^ 1][slot * 8], A + (size_t)ar * 1024 + (kt + 1) * 32 + seg * 8);
        async16(&Bs[cur ^ 1][slot * 8], Bw + (size_t)(n0 + row) * 1024 + (kt + 1) * 32 + seg * 8);
      }
    }
    const u16* Ac = cur ? &As[1][0] : &As[0][0];
    const u16* Bc = cur ? &Bs[1][0] : &Bs[0][0];
    bf16x8 a[8], b[4];
#pragma unroll
    for (int mi = 0; mi < 8; ++mi)
      a[mi] = *(const bf16x8*)&Ac[(wr * 128 + mi * 16 + fr) * 32 + fo * 8];
#pragma unroll
    for (int ni = 0; ni < 4; ++ni)
      b[ni] = *(const bf16x8*)&Bc[(wc * 64 + ni * 16 + fr) * 32 + fo * 8];
#pragma unroll
    for (int mi = 0; mi < 8; ++mi)
#pragma unroll
      for (int ni = 0; ni < 4; ++ni)
        acc[mi][ni] = __builtin_amdgcn_mfma_f32_16x16x32_bf16(a[mi], b[ni], acc[mi][ni], 0, 0, 0);
    __syncthreads();   // drains next-tile vmcnt + this tile's lgkm
  }

#pragma unroll
  for (int ni = 0; ni < 4; ++ni) {
    int n = n0 + wc * 64 + ni * 16 + fr;
    float bv = bias[n];
#pragma unroll
    for (int mi = 0; mi < 8; ++mi) {
#pragma unroll
      for (int r = 0; r < 4; ++r) {
        int m = m0 + wr * 128 + mi * 16 + fo * 4 + r;   // C/D: col=lane&15, row=(lane>>4)*4+reg
        if (m < M) {
          float v = acc[mi][ni][r] + bv;
          if (OUT_BF16) ((u16*)Cout)[(size_t)m * 1024 + n] = f2bf(v);
          else          ((float*)Cout)[(size_t)m * 1024 + n] = v;
        }
      }
    }
  }
}

// ---------------- rope Q + [B*S][H] -> [B][NH][S][HD]; 2 outputs/thread ----------------
__global__ __launch_bounds__(256) void rope_q(const u16* __restrict__ P,
                                              const float* __restrict__ tab,
                                              u16* __restrict__ R) {
  int idx = blockIdx.x * 256 + threadIdx.x;   // 8,192,000 = 512 bh * 500 s * 32 j
  int j = idx & 31;
  int t = idx >> 5;
  int s = t % 500;
  int bh = t / 500;
  int h = bh & 15, b = bh >> 4;
  size_t src = (size_t)(b * 500 + s) * 1024 + h * 64;
  float x0 = bf2f(P[src + j]);
  float x1 = bf2f(P[src + 32 + j]);
  float xe = bf2f(P[src + 2 * j]);
  float xo = bf2f(P[src + 2 * j + 1]);
  f32x2 cn = *(const f32x2*)(tab + (s * 32 + j) * 2);
  size_t dst = (size_t)t * 64;
  R[dst + j]      = f2bf(x0 * cn[0] - xo * cn[1]);   // d<32
  R[dst + 32 + j] = f2bf(x1 * cn[0] + xe * cn[1]);   // d>=32
}

// ---------------- K: rope + gather kept tokens -> pre-swizzled tiles [bh][tile][64][128B] ------
// image[row][byte B] = K_rope[tok(row)][ (B ^ ((row&7)<<4)) / 2 ]
__global__ __launch_bounds__(256) void gather_k(const u16* __restrict__ Pk,
                                                const float* __restrict__ tab,
                                                const u16* __restrict__ karr,
                                                const int* __restrict__ kept,
                                                u16* __restrict__ Ktg) {
  const int tile = blockIdx.x;
  const int bh = blockIdx.y;
  const int h = bh & 15, b = bh >> 4;
  if (tile * 64 >= kept[b]) return;
  char* out = (char*)(Ktg + ((size_t)bh * 8 + tile) * 4096);
  const int tid = threadIdx.x;
#pragma unroll
  for (int i = 0; i < 8; ++i) {
    int item = i * 256 + tid;            // 2048 = 64 rows * 32 j
    int row = item >> 5, j = item & 31;
    int tok = karr[b * 512 + tile * 64 + row];
    int sw = (row & 7) << 4;
    u16 o0 = 0, o1 = 0;
    if (tok != 0xFFFF) {
      const u16* src = Pk + ((size_t)b * 500 + tok) * 1024 + h * 64;
      float x0 = bf2f(src[j]);
      float x1 = bf2f(src[32 + j]);
      float xe = bf2f(src[2 * j]);
      float xo = bf2f(src[2 * j + 1]);
      f32x2 cn = *(const f32x2*)(tab + (tok * 32 + j) * 2);
      o0 = f2bf(x0 * cn[0] - xo * cn[1]);
      o1 = f2bf(x1 * cn[0] + xe * cn[1]);
    }
    *(u16*)(out + row * 128 + ((2 * j) ^ sw)) = o0;
    *(u16*)(out + row * 128 + ((64 + 2 * j) ^ sw)) = o1;
  }
}

// ---------------- V: gather + transpose -> pre-swizzled V^T tiles [bh][tile][64 d][128B] ------
// image[d][byte B] = V[tok( (B ^ ((d&7)<<4))/2 )][d]
__global__ __launch_bounds__(256) void gather_v(const u16* __restrict__ Pv,
                                                const u16* __restrict__ karr,
                                                const int* __restrict__ kept,
                                                u16* __restrict__ Vtg) {
  const int tile = blockIdx.x;
  const int bh = blockIdx.y;
  const int h = bh & 15, b = bh >> 4;
  if (tile * 64 >= kept[b]) return;
  const int tid = threadIdx.x;
  __shared__ __attribute__((aligned(16))) u16 Vl[64 * 64];
#pragma unroll
  for (int i = 0; i < 2; ++i) {
    int chunk = i * 256 + tid;           // 512: slot(64) x seg(8)
    int slot = chunk >> 3, seg = chunk & 7;
    int tok = karr[b * 512 + tile * 64 + slot];
    bf16x8 v;
#pragma unroll
    for (int p = 0; p < 8; ++p) v[p] = 0;
    if (tok != 0xFFFF)
      v = *(const bf16x8*)(Pv + ((size_t)b * 500 + tok) * 1024 + h * 64 + seg * 8);
    *(bf16x8*)&Vl[slot * 64 + seg * 8] = v;
  }
  __syncthreads();
  u16* out = Vtg + ((size_t)bh * 8 + tile) * 4096;
#pragma unroll
  for (int i = 0; i < 2; ++i) {
    int chunk = i * 256 + tid;           // d(64) x c16(8)
    int d = chunk >> 3, c16 = chunk & 7;
    int k0 = ((c16 * 16) ^ ((d & 7) << 4)) >> 1;
    bf16x8 v;
#pragma unroll
    for (int p = 0; p < 8; ++p) v[p] = (short)Vl[(k0 + p) * 64 + d];
    *(bf16x8*)(out + chunk * 8) = v;
  }
}

// ---------------- flash attention: compressed k, swapped QK^T, in-reg softmax ----------------
// grid 2048: bid -> xcd-major so the 4 q-blocks of a head share an XCD (K/V L2 reuse).
// 8 waves x 16 q-rows = 128 q per block; k tiles of 64 kept positions.
__global__ __launch_bounds__(512) void attn_kernel(const u16* __restrict__ Qr,
                                                   const u16* __restrict__ Ktg,
                                                   const u16* __restrict__ Vtg,
                                                   const float* __restrict__ rel_emb,
                                                   const u16* __restrict__ karr,
                                                   const int* __restrict__ kept,
                                                   u16* __restrict__ AO) {
  const int bid = blockIdx.x;
  const int bh = ((bid >> 5) << 3) | (bid & 7);
  const int qb = (bid >> 3) & 3;
  const int h = bh & 15, b = bh >> 4;
  const int q0 = qb * 128;
  const int tid = threadIdx.x;
  const int wave = tid >> 6;
  const int fr = tid & 15, fo = (tid >> 4) & 3;

  __shared__ __attribute__((aligned(16))) u16 Ks[2][4096];   // 8KB pre-swizzled K tile x2
  __shared__ __attribute__((aligned(16))) u16 Vs[2][4096];   // 8KB pre-swizzled V^T tile x2
  __shared__ __attribute__((aligned(16))) u16 Pl[8][1024];   // per-wave P / epilogue bounce
  __shared__ float rel2[640];                                // rel window * log2e
  __shared__ u16 okk[512];                                   // orig token per slot (0xFFFF pad)

  const int nk = kept[b];
  const int nt = (nk + 63) >> 6;
  const float LOG2E = 1.44269504f;
  for (int i = tid; i < 640; i += 512) {
    int g = min(max(q0 - 12 + i, 0), 998);
    rel2[i] = rel_emb[g * 16 + h] * LOG2E;
  }
  okk[tid] = karr[b * 512 + tid];

  const int qloc = wave * 16 + fr;       // this lane's q (output column)
  const int qg = q0 + qloc;
  const bool qok = (qg < 500);
  const u16* Qb = Qr + ((size_t)bh * 500 + min(qg, 499)) * 64;
  bf16x8 qf0 = *(const bf16x8*)(Qb + fo * 8);        // B-frag: lane&15=q, fo*8=d-chunk
  bf16x8 qf1 = *(const bf16x8*)(Qb + 32 + fo * 8);

  f32x4 o[4];                            // o[nf][r]: d = nf*16+fo*4+r, q = fr (lane-local)
#pragma unroll
  for (int nf = 0; nf < 4; ++nf)
#pragma unroll
    for (int j = 0; j < 4; ++j) o[nf][j] = 0.f;
  float mrun = -1e30f, lrun = 0.f;       // per-lane scalars (q = fr)

  const u16* Kb = Ktg + (size_t)bh * 32768;
  const u16* Vb = Vtg + (size_t)bh * 32768;
  const int sw = (fr & 7) << 4;
  const float SC = 0.18033688f;          // 0.125 * log2(e)

  if (nt > 0) {
    async16(&Ks[0][tid * 8], Kb + tid * 8);
    async16(&Vs[0][tid * 8], Vb + tid * 8);
  }
  __syncthreads();

  for (int t = 0; t < nt; ++t) {
    const int cur = t & 1;
    if (t + 1 < nt) {                    // prefetch next tile into other buffer
      async16(&Ks[cur ^ 1][tid * 8], Kb + (t + 1) * 4096 + tid * 8);
      async16(&Vs[cur ^ 1][tid * 8], Vb + (t + 1) * 4096 + tid * 8);
    }
    const char* Kt = (const char*)(cur ? &Ks[1][0] : &Ks[0][0]);
    const char* Vt = (const char*)(cur ? &Vs[1][0] : &Vs[0][0]);

    // swapped QK^T: C[k][q] -> lane holds k = nf*16+fo*4+r for its q=fr
    f32x4 sacc[4];
    __builtin_amdgcn_s_setprio(1);
#pragma unroll
    for (int nf = 0; nf < 4; ++nf) {
#pragma unroll
      for (int jj = 0; jj < 4; ++jj) sacc[nf][jj] = 0.f;
      int rb = (nf * 16 + fr) * 128;
      bf16x8 kb0 = *(const bf16x8*)(Kt + rb + ((fo * 16) ^ sw));
      bf16x8 kb1 = *(const bf16x8*)(Kt + rb + ((64 + fo * 16) ^ sw));
      sacc[nf] = __builtin_amdgcn_mfma_f32_16x16x32_bf16(kb0, qf0, sacc[nf], 0, 0, 0);
      sacc[nf] = __builtin_amdgcn_mfma_f32_16x16x32_bf16(kb1, qf1, sacc[nf], 0, 0, 0);
    }
    __builtin_amdgcn_s_setprio(0);

    // scores (log2 domain) + in-register row max
    float p2[4][4];
    float pmax = -1e30f;
#pragma unroll
    for (int nf = 0; nf < 4; ++nf) {
#pragma unroll
      for (int r = 0; r < 4; ++r) {
        int slot = t * 64 + nf * 16 + fo * 4 + r;
        int ok = okk[slot];
        float rv = rel2[min(max(qloc - ok + 511, 0), 639)];
        bool valid = (ok != 0xFFFF) && qok;
        float s2 = valid ? fmaf(sacc[nf][r], SC, rv) : -1e30f;
        p2[nf][r] = s2;
        pmax = fmaxf(pmax, s2);
      }
    }
    pmax = fmaxf(pmax, __shfl_xor(pmax, 16, 64));
    pmax = fmaxf(pmax, __shfl_xor(pmax, 32, 64));

    if (!__all(pmax <= mrun + 8.0f)) {   // defer-max (T13): skip rescale on small growth
      float mnew = fmaxf(mrun, pmax);
      float scl = EXP2(mrun - mnew);
      lrun *= scl;
#pragma unroll
      for (int nf = 0; nf < 4; ++nf)
#pragma unroll
        for (int r = 0; r < 4; ++r) o[nf][r] *= scl;
      mrun = mnew;
    }

    float lsum = 0.f;
#pragma unroll
    for (int nf = 0; nf < 4; ++nf) {
      float e0 = EXP2(p2[nf][0] - mrun);
      float e1 = EXP2(p2[nf][1] - mrun);
      float e2 = EXP2(p2[nf][2] - mrun);
      float e3 = EXP2(p2[nf][3] - mrun);
      lsum += (e0 + e1) + (e2 + e3);
      uint2 w; w.x = packbf(e0, e1); w.y = packbf(e2, e3);
      *(uint2*)((char*)&Pl[wave][0] + fr * 128 + ((nf * 32 + fo * 8) ^ sw)) = w;
    }
    lsum += __shfl_xor(lsum, 16, 64);
    lsum += __shfl_xor(lsum, 32, 64);
    lrun += lsum;

    // PV flipped: mfma(V^T, P) -> C[d][q], q stays lane-local
    bf16x8 pa0 = *(const bf16x8*)((char*)&Pl[wave][0] + fr * 128 + ((fo * 16) ^ sw));
    bf16x8 pa1 = *(const bf16x8*)((char*)&Pl[wave][0] + fr * 128 + ((64 + fo * 16) ^ sw));
    __builtin_amdgcn_s_setprio(1);
#pragma unroll
    for (int nf = 0; nf < 4; ++nf) {
      int rb = (nf * 16 + fr) * 128;
      bf16x8 vb0 = *(const bf16x8*)(Vt + rb + ((fo * 16) ^ sw));
      bf16x8 vb1 = *(const bf16x8*)(Vt + rb + ((64 + fo * 16) ^ sw));
      o[nf] = __builtin_amdgcn_mfma_f32_16x16x32_bf16(vb0, pa0, o[nf], 0, 0, 0);
      o[nf] = __builtin_amdgcn_mfma_f32_16x16x32_bf16(vb1, pa1, o[nf], 0, 0, 0);
    }
    __builtin_amdgcn_s_setprio(0);
    __syncthreads();
  }

  // epilogue: per-lane normalize+clip, LDS bounce for coalesced stores
  float inv = (lrun > 0.f) ? 1.f / lrun : 0.f;
#pragma unroll
  for (int nf = 0; nf < 4; ++nf) {
    float v0 = fminf(fmaxf(o[nf][0] * inv, -30.f), 30.f);
    float v1 = fminf(fmaxf(o[nf][1] * inv, -30.f), 30.f);
    float v2 = fminf(fmaxf(o[nf][2] * inv, -30.f), 30.f);
    float v3 = fminf(fmaxf(o[nf][3] * inv, -30.f), 30.f);
    uint2 w; w.x = packbf(v0, v1); w.y = packbf(v2, v3);
    *(uint2*)((char*)&Pl[wave][0] + fr * 128 + ((nf * 32 + fo * 8) ^ sw)) = w;
  }
  {
    int lane = tid & 63;
    int ro = lane >> 2, c = lane & 3;
    int swr = (ro & 7) << 4;
    const char* Pw = (const char*)&Pl[wave][0];
    bf16x8 v0 = *(const bf16x8*)(Pw + ro * 128 + ((c * 32) ^ swr));
    bf16x8 v1 = *(const bf16x8*)(Pw + ro * 128 + ((c * 32 + 16) ^ swr));
    int token = q0 + wave * 16 + ro;
    if (token < 500) {
      u16* dst = AO + (size_t)(b * 500 + token) * 1024 + h * 64 + c * 16;
      *(bf16x8*)dst = v0;
      *(bf16x8*)(dst + 8) = v1;
    }
  }
}

// ---------------- launch ----------------
extern "C" void kernel_launch(void* const* d_in, const int* in_sizes, int n_in,
                              void* d_out, int out_size, void* d_ws, size_t ws_size,
                              hipStream_t stream) {
  const float* query = (const float*)d_in[0];
  const float* key_  = (const float*)d_in[1];
  const float* value = (const float*)d_in[2];
  const void*  mask  = d_in[3];
  const float* Wq = (const float*)d_in[4];
  const float* bq = (const float*)d_in[5];
  const float* Wk = (const float*)d_in[6];
  const float* bk = (const float*)d_in[7];
  const float* Wv = (const float*)d_in[8];
  const float* bv = (const float*)d_in[9];
  const float* Wo = (const float*)d_in[10];
  const float* bo = (const float*)d_in[11];
  const float* rel = (const float*)d_in[12];

  // ws map: Wb 8.39MB | 4 slots x 32MiB | misc ~0.26MB | 1MB pad (GEMM edge-read slack)
  // slot liveness: A: Xq->Pk->Vtg | B: Xk->Qro | C: Xv->Pq->Ktg | D: Pv->AO
  char* ws = (char*)d_ws;
  const size_t SLOT = 33554432;
  u16* Wb = (u16*)ws;
  char* Aq = ws + 8388608;
  char* Bq = Aq + SLOT;
  char* Cq = Bq + SLOT;
  char* Dq = Cq + SLOT;
  char* MISC = Dq + SLOT;
  u8*  maskb = (u8*)MISC;
  u16* karr  = (u16*)(MISC + 65536);
  int* kept  = (int*)(MISC + 131072);
  float* tab = (float*)(MISC + 131584);

  mask_prep<<<1, 256, 0, stream>>>(mask, maskb);
  build_gather<<<32, 512, 0, stream>>>(maskb, karr, kept);
  rope_table<<<63, 256, 0, stream>>>(tab);

  cvt_f32_bf16<<<512, 256, 0, stream>>>(Wq, Wb + 0 * 1048576, 262144);
  cvt_f32_bf16<<<512, 256, 0, stream>>>(Wk, Wb + 1 * 1048576, 262144);
  cvt_f32_bf16<<<512, 256, 0, stream>>>(Wv, Wb + 2 * 1048576, 262144);
  cvt_f32_bf16<<<512, 256, 0, stream>>>(Wo, Wb + 3 * 1048576, 262144);
  cvt_f32_bf16<<<2048, 256, 0, stream>>>(query, (u16*)Aq, 4096000);
  cvt_f32_bf16<<<2048, 256, 0, stream>>>(key_,  (u16*)Bq, 4096000);
  cvt_f32_bf16<<<2048, 256, 0, stream>>>(value, (u16*)Cq, 4096000);

  dim3 gg(63, 4);   // ceil(16000/256) x 1024/256
  gemm_bt<true><<<gg, 512, 0, stream>>>((u16*)Cq, Wb + 2 * 1048576, bv, Dq, 16000);  // Pv=D
  gemm_bt<true><<<gg, 512, 0, stream>>>((u16*)Aq, Wb + 0 * 1048576, bq, Cq, 16000);  // Pq=C
  gemm_bt<true><<<gg, 512, 0, stream>>>((u16*)Bq, Wb + 1 * 1048576, bk, Aq, 16000);  // Pk=A

  rope_q<<<32000, 256, 0, stream>>>((u16*)Cq, tab, (u16*)Bq);                   // Qro=B
  gather_k<<<dim3(8, 512), 256, 0, stream>>>((u16*)Aq, tab, karr, kept, (u16*)Cq);  // Ktg=C
  gather_v<<<dim3(8, 512), 256, 0, stream>>>((u16*)Dq, karr, kept, (u16*)Aq);       // Vtg=A

  attn_kernel<<<2048, 512, 0, stream>>>((u16*)Bq, (u16*)Cq, (u16*)Aq, rel,
                                        karr, kept, (u16*)Dq);                  // AO=D

  gemm_bt<false><<<gg, 512, 0, stream>>>((u16*)Dq, Wb + 3 * 1048576, bo, (float*)d_out, 16000);
}

// Round 7
// 450.090 us; speedup vs baseline: 1.0259x; 1.0259x over previous
//
#include <hip/hip_runtime.h>
#include <math.h>

// FlashMultiHeadAttention: B=32 S=500 H=1024 NH=16 HD=64, rope + rel-pos-bias + key-pad mask.
// Pipeline: [mask->bytes] [gather-list scan] [rope table] [f32->bf16 cvt]
//           [QKV proj GEMM 256x256 8-wave, depth-2 counted-vmcnt pipeline, XCD-chunked]
//           [rope Q] [rope+gather+swizzle K tiles] [gather+transpose+swizzle V tiles]
//           [flash attn: masked-k compressed, swapped QK^T, in-reg softmax] [out proj GEMM]

typedef unsigned short u16;
typedef unsigned int   u32;
typedef unsigned char  u8;
using bf16x8 = __attribute__((ext_vector_type(8))) short;
using f32x4  = __attribute__((ext_vector_type(4))) float;
using f32x2  = __attribute__((ext_vector_type(2))) float;
using u16x4  = __attribute__((ext_vector_type(4))) unsigned short;

#define DEV __device__ __forceinline__

#if __has_builtin(__builtin_amdgcn_exp2f)
#define EXP2(x) __builtin_amdgcn_exp2f(x)
#else
#define EXP2(x) exp2f(x)
#endif

DEV u16 f2bf(float f) {                 // RNE f32 -> bf16
  union { float f; u32 u; } c; c.f = f;
  u32 u = c.u;
  return (u16)((u + 0x7FFFu + ((u >> 16) & 1u)) >> 16);
}
DEV float bf2f(u16 h) {
  union { u32 u; float f; } c; c.u = ((u32)h) << 16;
  return c.f;
}
DEV u32 packbf(float a, float b) {      // half-up rounding, packed pair
  union { float f; u32 u; } x, y; x.f = a; y.f = b;
  return ((x.u + 0x8000u) >> 16) | ((y.u + 0x8000u) & 0xFFFF0000u);
}

// async global->LDS, 16B/lane; LDS dest = wave-uniform base + lane*16 (linear).
DEV void async16(void* l, const void* g) {
  __builtin_amdgcn_global_load_lds(
      (__attribute__((address_space(1))) unsigned int*)g,
      (__attribute__((address_space(3))) unsigned int*)l, 16, 0, 0);
}

// ---------------- mask prep: detect bool storage (i32/f32/u8), emit bytes ----------------
__global__ __launch_bounds__(256) void mask_prep(const void* __restrict__ mraw,
                                                 u8* __restrict__ maskb) {
  __shared__ int bad_i32, bad_f32;
  if (threadIdx.x == 0) { bad_i32 = 0; bad_f32 = 0; }
  __syncthreads();
  const u32* w = (const u32*)mraw;
  int li = 0, lf = 0;
  for (int g = threadIdx.x; g < 4000; g += 256) {
    u32 v = w[g];
    li |= !(v == 0u || v == 1u);
    lf |= !(v == 0u || v == 0x3F800000u);
  }
  if (li) atomicOr(&bad_i32, 1);
  if (lf) atomicOr(&bad_f32, 1);
  __syncthreads();
  int mode = (!bad_i32) ? 0 : ((!bad_f32) ? 1 : 2);   // 0=int32, 1=float32, 2=uint8
  for (int i = threadIdx.x; i < 16000; i += 256) {
    int v;
    if (mode == 0)      v = ((const int*)mraw)[i] != 0;
    else if (mode == 1) v = (((const float*)mraw)[i] != 0.0f);
    else                v = ((const u8*)mraw)[i] != 0;
    maskb[i] = (u8)v;
  }
}

// ---------------- per-batch gather list: karr[b][512] = kept token or 0xFFFF ----------------
__global__ __launch_bounds__(512) void build_gather(const u8* __restrict__ maskb,
                                                    u16* __restrict__ karr,
                                                    int* __restrict__ kept) {
  const int b = blockIdx.x;
  const int t = threadIdx.x;
  const int lane = t & 63, wave = t >> 6;
  __shared__ int wbase[8];
  __shared__ int wpop[8];
  int v = (t < 500) ? (int)maskb[b * 500 + t] : 0;
  unsigned long long bal = __ballot(v != 0);
  karr[b * 512 + t] = 0xFFFF;
  if (lane == 0) wpop[wave] = __popcll(bal);
  __syncthreads();
  if (t == 0) {
    int s = 0;
    for (int w = 0; w < 8; ++w) { wbase[w] = s; s += wpop[w]; }
    kept[b] = s;
  }
  __syncthreads();
  if (v) {
    int rank = wbase[wave] + __popcll(bal & ((1ull << lane) - 1ull));
    karr[b * 512 + rank] = (u16)t;
  }
}

// ---------------- rope cos/sin table: tab[(s*32+j)*2] = cos, +1 = sin ----------------
__global__ __launch_bounds__(256) void rope_table(float* __restrict__ tab) {
  int idx = blockIdx.x * 256 + threadIdx.x;
  if (idx >= 16000) return;
  int s = idx >> 5, j = idx & 31;
  float ang = (float)s * exp2f(-(float)j * 0.41524100f);  // 10000^(-j/32)
  float sn, cs;
  sincosf(ang, &sn, &cs);
  tab[idx * 2] = cs;
  tab[idx * 2 + 1] = sn;
}

// ---------------- f32 -> bf16 convert (vectorized) ----------------
__global__ __launch_bounds__(256) void cvt_f32_bf16(const float* __restrict__ src,
                                                    u16* __restrict__ dst, int n4) {
  int i = blockIdx.x * 256 + threadIdx.x;
  int stride = gridDim.x * 256;
  for (; i < n4; i += stride) {
    f32x4 f = *(const f32x4*)(src + (size_t)i * 4);
    u16x4 o;
    o[0] = f2bf(f[0]); o[1] = f2bf(f[1]); o[2] = f2bf(f[2]); o[3] = f2bf(f[3]);
    *(u16x4*)(dst + (size_t)i * 4) = o;
  }
}

// ---------------- GEMM: C[m][n] = sum_k A[m][k]*Bw[n][k] + bias[n] ----------------
// 256x256 tile, BK=32, 512 thr / 8 waves (2x4), per-wave 128x64.
// Depth-2 prefetch, 3 LDS buffers (96KB), counted vmcnt (never drain in loop),
// raw s_barrier. 1D grid 252, bijective XCD chunking (A-panel L2 reuse per XCD).
template <bool OUT_BF16>
__global__ __launch_bounds__(512, 1) void gemm_bt(const u16* __restrict__ A,
                                                  const u16* __restrict__ Bw,
                                                  const float* __restrict__ bias,
                                                  void* __restrict__ Cout, int M) {
  const int bid = blockIdx.x;
  const int xcd = bid & 7, idx = bid >> 3;            // dispatch round-robins XCDs
  const int swz = (xcd < 4 ? xcd * 32 : 128 + (xcd - 4) * 31) + idx;  // 252 = 4*32+4*31
  const int m0 = (swz >> 2) * 256;                    // consecutive swz share A panel
  const int n0 = (swz & 3) * 256;
  const int tid = threadIdx.x;
  const int wave = tid >> 6;
  const int wr = wave >> 2, wc = wave & 3;
  const int fr = tid & 15, fo = (tid >> 4) & 3;

  const int TILE = 256 * 32;                          // u16 elems per buffer
  __shared__ __attribute__((aligned(16))) u16 As[3 * 256 * 32];   // 48KB
  __shared__ __attribute__((aligned(16))) u16 Bs[3 * 256 * 32];   // 48KB

  f32x4 acc[8][4];
#pragma unroll
  for (int mi = 0; mi < 8; ++mi)
#pragma unroll
    for (int ni = 0; ni < 4; ++ni)
#pragma unroll
      for (int j = 0; j < 4; ++j) acc[mi][ni][j] = 0.f;

  auto STAGE = [&](int kt2, u16* sA, u16* sB) {
#pragma unroll
    for (int i = 0; i < 2; ++i) {
      int slot = i * 512 + tid;                       // 1024 slots of 16B per matrix
      int row = slot >> 2, seg = slot & 3;
      int ar = min(m0 + row, M - 1);
      async16(&sA[slot * 8], A + (size_t)ar * 1024 + kt2 * 32 + seg * 8);
      async16(&sB[slot * 8], Bw + (size_t)(n0 + row) * 1024 + kt2 * 32 + seg * 8);
    }
  };

  u16 *a0 = &As[0], *a1 = &As[TILE], *a2 = &As[2 * TILE];
  u16 *b0 = &Bs[0], *b1 = &Bs[TILE], *b2 = &Bs[2 * TILE];
  STAGE(0, a0, b0);                                   // 4 vmem ops
  STAGE(1, a1, b1);                                   // 4 more in flight

  for (int kt = 0; kt < 32; ++kt) {
    if (kt + 2 < 32) {
      STAGE(kt + 2, a2, b2);                          // overwrites tile kt-1's buffer
      asm volatile("s_waitcnt vmcnt(8)" ::: "memory");   // tile kt landed; kt+1/kt+2 fly
    } else if (kt + 1 < 32) {
      asm volatile("s_waitcnt vmcnt(4)" ::: "memory");
    } else {
      asm volatile("s_waitcnt vmcnt(0)" ::: "memory");
    }
    __builtin_amdgcn_s_barrier();                     // all waves see tile kt in LDS

    bf16x8 a[8], b[4];
#pragma unroll
    for (int mi = 0; mi < 8; ++mi)
      a[mi] = *(const bf16x8*)&a0[(wr * 128 + mi * 16 + fr) * 32 + fo * 8];
#pragma unroll
    for (int ni = 0; ni < 4; ++ni)
      b[ni] = *(const bf16x8*)&b0[(wc * 64 + ni * 16 + fr) * 32 + fo * 8];
#pragma unroll
    for (int mi = 0; mi < 8; ++mi)
#pragma unroll
      for (int ni = 0; ni < 4; ++ni)
        acc[mi][ni] = __builtin_amdgcn_mfma_f32_16x16x32_bf16(a[mi], b[ni], acc[mi][ni], 0, 0, 0);

    asm volatile("s_waitcnt lgkmcnt(0)" ::: "memory");  // my ds_reads of a0/b0 done
    __builtin_amdgcn_s_barrier();                       // everyone done -> buffer reusable
    u16* t;
    t = a0; a0 = a1; a1 = a2; a2 = t;
    t = b0; b0 = b1; b1 = b2; b2 = t;
  }

#pragma unroll
  for (int ni = 0; ni < 4; ++ni) {
    int n = n0 + wc * 64 + ni * 16 + fr;
    float bv = bias[n];
#pragma unroll
    for (int mi = 0; mi < 8; ++mi) {
#pragma unroll
      for (int r = 0; r < 4; ++r) {
        int m = m0 + wr * 128 + mi * 16 + fo * 4 + r;   // C/D: col=lane&15, row=(lane>>4)*4+reg
        if (m < M) {
          float v = acc[mi][ni][r] + bv;
          if (OUT_BF16) ((u16*)Cout)[(size_t)m * 1024 + n] = f2bf(v);
          else          ((float*)Cout)[(size_t)m * 1024 + n] = v;
        }
      }
    }
  }
}

// ---------------- rope Q + [B*S][H] -> [B][NH][S][HD]; 2 outputs/thread ----------------
__global__ __launch_bounds__(256) void rope_q(const u16* __restrict__ P,
                                              const float* __restrict__ tab,
                                              u16* __restrict__ R) {
  int idx = blockIdx.x * 256 + threadIdx.x;   // 8,192,000 = 512 bh * 500 s * 32 j
  int j = idx & 31;
  int t = idx >> 5;
  int s = t % 500;
  int bh = t / 500;
  int h = bh & 15, b = bh >> 4;
  size_t src = (size_t)(b * 500 + s) * 1024 + h * 64;
  float x0 = bf2f(P[src + j]);
  float x1 = bf2f(P[src + 32 + j]);
  float xe = bf2f(P[src + 2 * j]);
  float xo = bf2f(P[src + 2 * j + 1]);
  f32x2 cn = *(const f32x2*)(tab + (s * 32 + j) * 2);
  size_t dst = (size_t)t * 64;
  R[dst + j]      = f2bf(x0 * cn[0] - xo * cn[1]);   // d<32
  R[dst + 32 + j] = f2bf(x1 * cn[0] + xe * cn[1]);   // d>=32
}

// ---------------- K: rope + gather kept tokens -> pre-swizzled tiles [bh][tile][64][128B] ------
__global__ __launch_bounds__(256) void gather_k(const u16* __restrict__ Pk,
                                                const float* __restrict__ tab,
                                                const u16* __restrict__ karr,
                                                const int* __restrict__ kept,
                                                u16* __restrict__ Ktg) {
  const int tile = blockIdx.x;
  const int bh = blockIdx.y;
  const int h = bh & 15, b = bh >> 4;
  if (tile * 64 >= kept[b]) return;
  char* out = (char*)(Ktg + ((size_t)bh * 8 + tile) * 4096);
  const int tid = threadIdx.x;
#pragma unroll
  for (int i = 0; i < 8; ++i) {
    int item = i * 256 + tid;            // 2048 = 64 rows * 32 j
    int row = item >> 5, j = item & 31;
    int tok = karr[b * 512 + tile * 64 + row];
    int sw = (row & 7) << 4;
    u16 o0 = 0, o1 = 0;
    if (tok != 0xFFFF) {
      const u16* src = Pk + ((size_t)b * 500 + tok) * 1024 + h * 64;
      float x0 = bf2f(src[j]);
      float x1 = bf2f(src[32 + j]);
      float xe = bf2f(src[2 * j]);
      float xo = bf2f(src[2 * j + 1]);
      f32x2 cn = *(const f32x2*)(tab + (tok * 32 + j) * 2);
      o0 = f2bf(x0 * cn[0] - xo * cn[1]);
      o1 = f2bf(x1 * cn[0] + xe * cn[1]);
    }
    *(u16*)(out + row * 128 + ((2 * j) ^ sw)) = o0;
    *(u16*)(out + row * 128 + ((64 + 2 * j) ^ sw)) = o1;
  }
}

// ---------------- V: gather + transpose -> pre-swizzled V^T tiles [bh][tile][64 d][128B] ------
__global__ __launch_bounds__(256) void gather_v(const u16* __restrict__ Pv,
                                                const u16* __restrict__ karr,
                                                const int* __restrict__ kept,
                                                u16* __restrict__ Vtg) {
  const int tile = blockIdx.x;
  const int bh = blockIdx.y;
  const int h = bh & 15, b = bh >> 4;
  if (tile * 64 >= kept[b]) return;
  const int tid = threadIdx.x;
  __shared__ __attribute__((aligned(16))) u16 Vl[64 * 64];
#pragma unroll
  for (int i = 0; i < 2; ++i) {
    int chunk = i * 256 + tid;           // 512: slot(64) x seg(8)
    int slot = chunk >> 3, seg = chunk & 7;
    int tok = karr[b * 512 + tile * 64 + slot];
    bf16x8 v;
#pragma unroll
    for (int p = 0; p < 8; ++p) v[p] = 0;
    if (tok != 0xFFFF)
      v = *(const bf16x8*)(Pv + ((size_t)b * 500 + tok) * 1024 + h * 64 + seg * 8);
    *(bf16x8*)&Vl[slot * 64 + seg * 8] = v;
  }
  __syncthreads();
  u16* out = Vtg + ((size_t)bh * 8 + tile) * 4096;
#pragma unroll
  for (int i = 0; i < 2; ++i) {
    int chunk = i * 256 + tid;           // d(64) x c16(8)
    int d = chunk >> 3, c16 = chunk & 7;
    int k0 = ((c16 * 16) ^ ((d & 7) << 4)) >> 1;
    bf16x8 v;
#pragma unroll
    for (int p = 0; p < 8; ++p) v[p] = (short)Vl[(k0 + p) * 64 + d];
    *(bf16x8*)(out + chunk * 8) = v;
  }
}

// ---------------- flash attention: compressed k, swapped QK^T, in-reg softmax ----------------
__global__ __launch_bounds__(512) void attn_kernel(const u16* __restrict__ Qr,
                                                   const u16* __restrict__ Ktg,
                                                   const u16* __restrict__ Vtg,
                                                   const float* __restrict__ rel_emb,
                                                   const u16* __restrict__ karr,
                                                   const int* __restrict__ kept,
                                                   u16* __restrict__ AO) {
  const int bid = blockIdx.x;
  const int bh = ((bid >> 5) << 3) | (bid & 7);
  const int qb = (bid >> 3) & 3;
  const int h = bh & 15, b = bh >> 4;
  const int q0 = qb * 128;
  const int tid = threadIdx.x;
  const int wave = tid >> 6;
  const int fr = tid & 15, fo = (tid >> 4) & 3;

  __shared__ __attribute__((aligned(16))) u16 Ks[2][4096];
  __shared__ __attribute__((aligned(16))) u16 Vs[2][4096];
  __shared__ __attribute__((aligned(16))) u16 Pl[8][1024];
  __shared__ float rel2[640];
  __shared__ u16 okk[512];

  const int nk = kept[b];
  const int nt = (nk + 63) >> 6;
  const float LOG2E = 1.44269504f;
  for (int i = tid; i < 640; i += 512) {
    int g = min(max(q0 - 12 + i, 0), 998);
    rel2[i] = rel_emb[g * 16 + h] * LOG2E;
  }
  okk[tid] = karr[b * 512 + tid];

  const int qloc = wave * 16 + fr;
  const int qg = q0 + qloc;
  const bool qok = (qg < 500);
  const u16* Qb = Qr + ((size_t)bh * 500 + min(qg, 499)) * 64;
  bf16x8 qf0 = *(const bf16x8*)(Qb + fo * 8);
  bf16x8 qf1 = *(const bf16x8*)(Qb + 32 + fo * 8);

  f32x4 o[4];
#pragma unroll
  for (int nf = 0; nf < 4; ++nf)
#pragma unroll
    for (int j = 0; j < 4; ++j) o[nf][j] = 0.f;
  float mrun = -1e30f, lrun = 0.f;

  const u16* Kb = Ktg + (size_t)bh * 32768;
  const u16* Vb = Vtg + (size_t)bh * 32768;
  const int sw = (fr & 7) << 4;
  const float SC = 0.18033688f;          // 0.125 * log2(e)

  if (nt > 0) {
    async16(&Ks[0][tid * 8], Kb + tid * 8);
    async16(&Vs[0][tid * 8], Vb + tid * 8);
  }
  __syncthreads();

  for (int t = 0; t < nt; ++t) {
    const int cur = t & 1;
    if (t + 1 < nt) {
      async16(&Ks[cur ^ 1][tid * 8], Kb + (t + 1) * 4096 + tid * 8);
      async16(&Vs[cur ^ 1][tid * 8], Vb + (t + 1) * 4096 + tid * 8);
    }
    const char* Kt = (const char*)(cur ? &Ks[1][0] : &Ks[0][0]);
    const char* Vt = (const char*)(cur ? &Vs[1][0] : &Vs[0][0]);

    f32x4 sacc[4];
    __builtin_amdgcn_s_setprio(1);
#pragma unroll
    for (int nf = 0; nf < 4; ++nf) {
#pragma unroll
      for (int jj = 0; jj < 4; ++jj) sacc[nf][jj] = 0.f;
      int rb = (nf * 16 + fr) * 128;
      bf16x8 kb0 = *(const bf16x8*)(Kt + rb + ((fo * 16) ^ sw));
      bf16x8 kb1 = *(const bf16x8*)(Kt + rb + ((64 + fo * 16) ^ sw));
      sacc[nf] = __builtin_amdgcn_mfma_f32_16x16x32_bf16(kb0, qf0, sacc[nf], 0, 0, 0);
      sacc[nf] = __builtin_amdgcn_mfma_f32_16x16x32_bf16(kb1, qf1, sacc[nf], 0, 0, 0);
    }
    __builtin_amdgcn_s_setprio(0);

    float p2[4][4];
    float pmax = -1e30f;
#pragma unroll
    for (int nf = 0; nf < 4; ++nf) {
#pragma unroll
      for (int r = 0; r < 4; ++r) {
        int slot = t * 64 + nf * 16 + fo * 4 + r;
        int ok = okk[slot];
        float rv = rel2[min(max(qloc - ok + 511, 0), 639)];
        bool valid = (ok != 0xFFFF) && qok;
        float s2 = valid ? fmaf(sacc[nf][r], SC, rv) : -1e30f;
        p2[nf][r] = s2;
        pmax = fmaxf(pmax, s2);
      }
    }
    pmax = fmaxf(pmax, __shfl_xor(pmax, 16, 64));
    pmax = fmaxf(pmax, __shfl_xor(pmax, 32, 64));

    if (!__all(pmax <= mrun + 8.0f)) {   // defer-max (T13)
      float mnew = fmaxf(mrun, pmax);
      float scl = EXP2(mrun - mnew);
      lrun *= scl;
#pragma unroll
      for (int nf = 0; nf < 4; ++nf)
#pragma unroll
        for (int r = 0; r < 4; ++r) o[nf][r] *= scl;
      mrun = mnew;
    }

    float lsum = 0.f;
#pragma unroll
    for (int nf = 0; nf < 4; ++nf) {
      float e0 = EXP2(p2[nf][0] - mrun);
      float e1 = EXP2(p2[nf][1] - mrun);
      float e2 = EXP2(p2[nf][2] - mrun);
      float e3 = EXP2(p2[nf][3] - mrun);
      lsum += (e0 + e1) + (e2 + e3);
      uint2 w; w.x = packbf(e0, e1); w.y = packbf(e2, e3);
      *(uint2*)((char*)&Pl[wave][0] + fr * 128 + ((nf * 32 + fo * 8) ^ sw)) = w;
    }
    lsum += __shfl_xor(lsum, 16, 64);
    lsum += __shfl_xor(lsum, 32, 64);
    lrun += lsum;

    bf16x8 pa0 = *(const bf16x8*)((char*)&Pl[wave][0] + fr * 128 + ((fo * 16) ^ sw));
    bf16x8 pa1 = *(const bf16x8*)((char*)&Pl[wave][0] + fr * 128 + ((64 + fo * 16) ^ sw));
    __builtin_amdgcn_s_setprio(1);
#pragma unroll
    for (int nf = 0; nf < 4; ++nf) {
      int rb = (nf * 16 + fr) * 128;
      bf16x8 vb0 = *(const bf16x8*)(Vt + rb + ((fo * 16) ^ sw));
      bf16x8 vb1 = *(const bf16x8*)(Vt + rb + ((64 + fo * 16) ^ sw));
      o[nf] = __builtin_amdgcn_mfma_f32_16x16x32_bf16(vb0, pa0, o[nf], 0, 0, 0);
      o[nf] = __builtin_amdgcn_mfma_f32_16x16x32_bf16(vb1, pa1, o[nf], 0, 0, 0);
    }
    __builtin_amdgcn_s_setprio(0);
    __syncthreads();
  }

  float inv = (lrun > 0.f) ? 1.f / lrun : 0.f;
#pragma unroll
  for (int nf = 0; nf < 4; ++nf) {
    float v0 = fminf(fmaxf(o[nf][0] * inv, -30.f), 30.f);
    float v1 = fminf(fmaxf(o[nf][1] * inv, -30.f), 30.f);
    float v2 = fminf(fmaxf(o[nf][2] * inv, -30.f), 30.f);
    float v3 = fminf(fmaxf(o[nf][3] * inv, -30.f), 30.f);
    uint2 w; w.x = packbf(v0, v1); w.y = packbf(v2, v3);
    *(uint2*)((char*)&Pl[wave][0] + fr * 128 + ((nf * 32 + fo * 8) ^ sw)) = w;
  }
  {
    int lane = tid & 63;
    int ro = lane >> 2, c = lane & 3;
    int swr = (ro & 7) << 4;
    const char* Pw = (const char*)&Pl[wave][0];
    bf16x8 v0 = *(const bf16x8*)(Pw + ro * 128 + ((c * 32) ^ swr));
    bf16x8 v1 = *(const bf16x8*)(Pw + ro * 128 + ((c * 32 + 16) ^ swr));
    int token = q0 + wave * 16 + ro;
    if (token < 500) {
      u16* dst = AO + (size_t)(b * 500 + token) * 1024 + h * 64 + c * 16;
      *(bf16x8*)dst = v0;
      *(bf16x8*)(dst + 8) = v1;
    }
  }
}

// ---------------- launch ----------------
extern "C" void kernel_launch(void* const* d_in, const int* in_sizes, int n_in,
                              void* d_out, int out_size, void* d_ws, size_t ws_size,
                              hipStream_t stream) {
  const float* query = (const float*)d_in[0];
  const float* key_  = (const float*)d_in[1];
  const float* value = (const float*)d_in[2];
  const void*  mask  = d_in[3];
  const float* Wq = (const float*)d_in[4];
  const float* bq = (const float*)d_in[5];
  const float* Wk = (const float*)d_in[6];
  const float* bk = (const float*)d_in[7];
  const float* Wv = (const float*)d_in[8];
  const float* bv = (const float*)d_in[9];
  const float* Wo = (const float*)d_in[10];
  const float* bo = (const float*)d_in[11];
  const float* rel = (const float*)d_in[12];

  // ws map: Wb 8.39MB | 4 slots x 32MiB | misc ~0.26MB
  // slot liveness: A: Xq->Pk->Vtg | B: Xk->Qro | C: Xv->Pq->Ktg | D: Pv->AO
  char* ws = (char*)d_ws;
  const size_t SLOT = 33554432;
  u16* Wb = (u16*)ws;
  char* Aq = ws + 8388608;
  char* Bq = Aq + SLOT;
  char* Cq = Bq + SLOT;
  char* Dq = Cq + SLOT;
  char* MISC = Dq + SLOT;
  u8*  maskb = (u8*)MISC;
  u16* karr  = (u16*)(MISC + 65536);
  int* kept  = (int*)(MISC + 131072);
  float* tab = (float*)(MISC + 131584);

  mask_prep<<<1, 256, 0, stream>>>(mask, maskb);
  build_gather<<<32, 512, 0, stream>>>(maskb, karr, kept);
  rope_table<<<63, 256, 0, stream>>>(tab);

  cvt_f32_bf16<<<512, 256, 0, stream>>>(Wq, Wb + 0 * 1048576, 262144);
  cvt_f32_bf16<<<512, 256, 0, stream>>>(Wk, Wb + 1 * 1048576, 262144);
  cvt_f32_bf16<<<512, 256, 0, stream>>>(Wv, Wb + 2 * 1048576, 262144);
  cvt_f32_bf16<<<512, 256, 0, stream>>>(Wo, Wb + 3 * 1048576, 262144);
  cvt_f32_bf16<<<2048, 256, 0, stream>>>(query, (u16*)Aq, 4096000);
  cvt_f32_bf16<<<2048, 256, 0, stream>>>(key_,  (u16*)Bq, 4096000);
  cvt_f32_bf16<<<2048, 256, 0, stream>>>(value, (u16*)Cq, 4096000);

  gemm_bt<true><<<252, 512, 0, stream>>>((u16*)Cq, Wb + 2 * 1048576, bv, Dq, 16000);  // Pv=D
  gemm_bt<true><<<252, 512, 0, stream>>>((u16*)Aq, Wb + 0 * 1048576, bq, Cq, 16000);  // Pq=C
  gemm_bt<true><<<252, 512, 0, stream>>>((u16*)Bq, Wb + 1 * 1048576, bk, Aq, 16000);  // Pk=A

  rope_q<<<32000, 256, 0, stream>>>((u16*)Cq, tab, (u16*)Bq);                   // Qro=B
  gather_k<<<dim3(8, 512), 256, 0, stream>>>((u16*)Aq, tab, karr, kept, (u16*)Cq);  // Ktg=C
  gather_v<<<dim3(8, 512), 256, 0, stream>>>((u16*)Dq, karr, kept, (u16*)Aq);       // Vtg=A

  attn_kernel<<<2048, 512, 0, stream>>>((u16*)Bq, (u16*)Cq, (u16*)Aq, rel,
                                        karr, kept, (u16*)Dq);                  // AO=D

  gemm_bt<false><<<252, 512, 0, stream>>>((u16*)Dq, Wb + 3 * 1048576, bo, (float*)d_out, 16000);
}

// Round 8
// 387.157 us; speedup vs baseline: 1.1927x; 1.1626x over previous
//
#include <hip/hip_runtime.h>
#include <math.h>

// FlashMultiHeadAttention: B=32 S=500 H=1024 NH=16 HD=64, rope + rel-pos-bias + key-pad mask.
// Pipeline: [mask->bytes] [gather-list scan] [rope table] [f32->bf16 cvt]
//           [QKV proj GEMM 256x256 8-wave, fine-phase counted-vmcnt pipeline, XCD-chunked]
//           [rope Q] [rope+gather+swizzle K tiles] [gather+transpose+swizzle V tiles]
//           [flash attn: masked-k compressed, swapped QK^T, in-reg softmax] [out proj GEMM]

typedef unsigned short u16;
typedef unsigned int   u32;
typedef unsigned char  u8;
using bf16x8 = __attribute__((ext_vector_type(8))) short;
using f32x4  = __attribute__((ext_vector_type(4))) float;
using f32x2  = __attribute__((ext_vector_type(2))) float;
using u16x4  = __attribute__((ext_vector_type(4))) unsigned short;

#define DEV __device__ __forceinline__

#if __has_builtin(__builtin_amdgcn_exp2f)
#define EXP2(x) __builtin_amdgcn_exp2f(x)
#else
#define EXP2(x) exp2f(x)
#endif

DEV u16 f2bf(float f) {                 // RNE f32 -> bf16
  union { float f; u32 u; } c; c.f = f;
  u32 u = c.u;
  return (u16)((u + 0x7FFFu + ((u >> 16) & 1u)) >> 16);
}
DEV float bf2f(u16 h) {
  union { u32 u; float f; } c; c.u = ((u32)h) << 16;
  return c.f;
}
DEV u32 packbf(float a, float b) {      // half-up rounding, packed pair
  union { float f; u32 u; } x, y; x.f = a; y.f = b;
  return ((x.u + 0x8000u) >> 16) | ((y.u + 0x8000u) & 0xFFFF0000u);
}

// async global->LDS, 16B/lane; LDS dest = wave-uniform base + lane*16 (linear).
DEV void async16(void* l, const void* g) {
  __builtin_amdgcn_global_load_lds(
      (__attribute__((address_space(1))) unsigned int*)g,
      (__attribute__((address_space(3))) unsigned int*)l, 16, 0, 0);
}

// ---------------- mask prep: detect bool storage (i32/f32/u8), emit bytes ----------------
__global__ __launch_bounds__(256) void mask_prep(const void* __restrict__ mraw,
                                                 u8* __restrict__ maskb) {
  __shared__ int bad_i32, bad_f32;
  if (threadIdx.x == 0) { bad_i32 = 0; bad_f32 = 0; }
  __syncthreads();
  const u32* w = (const u32*)mraw;
  int li = 0, lf = 0;
  for (int g = threadIdx.x; g < 4000; g += 256) {
    u32 v = w[g];
    li |= !(v == 0u || v == 1u);
    lf |= !(v == 0u || v == 0x3F800000u);
  }
  if (li) atomicOr(&bad_i32, 1);
  if (lf) atomicOr(&bad_f32, 1);
  __syncthreads();
  int mode = (!bad_i32) ? 0 : ((!bad_f32) ? 1 : 2);   // 0=int32, 1=float32, 2=uint8
  for (int i = threadIdx.x; i < 16000; i += 256) {
    int v;
    if (mode == 0)      v = ((const int*)mraw)[i] != 0;
    else if (mode == 1) v = (((const float*)mraw)[i] != 0.0f);
    else                v = ((const u8*)mraw)[i] != 0;
    maskb[i] = (u8)v;
  }
}

// ---------------- per-batch gather list: karr[b][512] = kept token or 0xFFFF ----------------
__global__ __launch_bounds__(512) void build_gather(const u8* __restrict__ maskb,
                                                    u16* __restrict__ karr,
                                                    int* __restrict__ kept) {
  const int b = blockIdx.x;
  const int t = threadIdx.x;
  const int lane = t & 63, wave = t >> 6;
  __shared__ int wbase[8];
  __shared__ int wpop[8];
  int v = (t < 500) ? (int)maskb[b * 500 + t] : 0;
  unsigned long long bal = __ballot(v != 0);
  karr[b * 512 + t] = 0xFFFF;
  if (lane == 0) wpop[wave] = __popcll(bal);
  __syncthreads();
  if (t == 0) {
    int s = 0;
    for (int w = 0; w < 8; ++w) { wbase[w] = s; s += wpop[w]; }
    kept[b] = s;
  }
  __syncthreads();
  if (v) {
    int rank = wbase[wave] + __popcll(bal & ((1ull << lane) - 1ull));
    karr[b * 512 + rank] = (u16)t;
  }
}

// ---------------- rope cos/sin table: tab[(s*32+j)*2] = cos, +1 = sin ----------------
__global__ __launch_bounds__(256) void rope_table(float* __restrict__ tab) {
  int idx = blockIdx.x * 256 + threadIdx.x;
  if (idx >= 16000) return;
  int s = idx >> 5, j = idx & 31;
  float ang = (float)s * exp2f(-(float)j * 0.41524100f);  // 10000^(-j/32)
  float sn, cs;
  sincosf(ang, &sn, &cs);
  tab[idx * 2] = cs;
  tab[idx * 2 + 1] = sn;
}

// ---------------- f32 -> bf16 convert (vectorized) ----------------
__global__ __launch_bounds__(256) void cvt_f32_bf16(const float* __restrict__ src,
                                                    u16* __restrict__ dst, int n4) {
  int i = blockIdx.x * 256 + threadIdx.x;
  int stride = gridDim.x * 256;
  for (; i < n4; i += stride) {
    f32x4 f = *(const f32x4*)(src + (size_t)i * 4);
    u16x4 o;
    o[0] = f2bf(f[0]); o[1] = f2bf(f[1]); o[2] = f2bf(f[2]); o[3] = f2bf(f[3]);
    *(u16x4*)(dst + (size_t)i * 4) = o;
  }
}

// ---------------- GEMM: C[m][n] = sum_k A[m][k]*Bw[n][k] + bias[n] ----------------
// 256x256 tile, BK=32, 512 thr / 8 waves (2x4), per-wave 128x64.
// Fine-phase schedule (T3+T4): per K-step 2 phases, each {ds_read || gload -> barrier
// -> lgkm(0)+sched_barrier -> setprio(1) 16xMFMA setprio(0) -> barrier}; vmcnt(4)
// once per K-step (never 0); tile kt+2 staged 2 iters ahead (3 buffers, 96KB LDS).
template <bool OUT_BF16>
__global__ __launch_bounds__(512, 2) void gemm_bt(const u16* __restrict__ A,
                                                  const u16* __restrict__ Bw,
                                                  const float* __restrict__ bias,
                                                  void* __restrict__ Cout, int M) {
  const int bid = blockIdx.x;
  const int xcd = bid & 7, idx = bid >> 3;            // dispatch round-robins XCDs
  const int swz = (xcd < 4 ? xcd * 32 : 128 + (xcd - 4) * 31) + idx;  // 252 = 4*32+4*31
  const int m0 = (swz >> 2) * 256;                    // consecutive swz share A panel
  const int n0 = (swz & 3) * 256;
  const int tid = threadIdx.x;
  const int wave = tid >> 6;
  const int wr = wave >> 2, wc = wave & 3;
  const int fr = tid & 15, fo = (tid >> 4) & 3;

  const int TILE = 256 * 32;                          // u16 elems per buffer
  __shared__ __attribute__((aligned(16))) u16 As[3 * 256 * 32];   // 48KB
  __shared__ __attribute__((aligned(16))) u16 Bs[3 * 256 * 32];   // 48KB

  f32x4 acc[8][4];
#pragma unroll
  for (int mi = 0; mi < 8; ++mi)
#pragma unroll
    for (int ni = 0; ni < 4; ++ni)
#pragma unroll
      for (int j = 0; j < 4; ++j) acc[mi][ni][j] = 0.f;

  auto STAGE_A = [&](int kt2, u16* sA) {
#pragma unroll
    for (int i = 0; i < 2; ++i) {
      int slot = i * 512 + tid;
      int row = slot >> 2, seg = slot & 3;
      int ar = min(m0 + row, M - 1);
      async16(&sA[slot * 8], A + (size_t)ar * 1024 + kt2 * 32 + seg * 8);
    }
  };
  auto STAGE_B = [&](int kt2, u16* sB) {
#pragma unroll
    for (int i = 0; i < 2; ++i) {
      int slot = i * 512 + tid;
      int row = slot >> 2, seg = slot & 3;
      async16(&sB[slot * 8], Bw + (size_t)(n0 + row) * 1024 + kt2 * 32 + seg * 8);
    }
  };

  u16 *a0 = &As[0], *a1 = &As[TILE], *a2 = &As[2 * TILE];
  u16 *b0 = &Bs[0], *b1 = &Bs[TILE], *b2 = &Bs[2 * TILE];
  STAGE_A(0, a0); STAGE_B(0, b0);                     // 4 vmem instrs (tile 0)
  STAGE_A(1, a1); STAGE_B(1, b1);                     // 4 more (tile 1)
  asm volatile("s_waitcnt vmcnt(4)" ::: "memory");    // tile 0 landed; tile 1 in flight
  __builtin_amdgcn_sched_barrier(0);
  __builtin_amdgcn_s_barrier();

  for (int kt = 0; kt < 32; ++kt) {
    const bool st = (kt + 2 < 32);
    // ---- phase 0: frags m0-3 + all b; stage A of kt+2 ----
    bf16x8 a[8], b[4];
#pragma unroll
    for (int mi = 0; mi < 4; ++mi)
      a[mi] = *(const bf16x8*)&a0[(wr * 128 + mi * 16 + fr) * 32 + fo * 8];
#pragma unroll
    for (int ni = 0; ni < 4; ++ni)
      b[ni] = *(const bf16x8*)&b0[(wc * 64 + ni * 16 + fr) * 32 + fo * 8];
    if (st) STAGE_A(kt + 2, a2);
    __builtin_amdgcn_s_barrier();
    asm volatile("s_waitcnt lgkmcnt(0)" ::: "memory");
    __builtin_amdgcn_sched_barrier(0);
    __builtin_amdgcn_s_setprio(1);
#pragma unroll
    for (int mi = 0; mi < 4; ++mi)
#pragma unroll
      for (int ni = 0; ni < 4; ++ni)
        acc[mi][ni] = __builtin_amdgcn_mfma_f32_16x16x32_bf16(a[mi], b[ni], acc[mi][ni], 0, 0, 0);
    __builtin_amdgcn_s_setprio(0);
    __builtin_amdgcn_s_barrier();

    // ---- phase 1: frags m4-7; stage B of kt+2 ----
#pragma unroll
    for (int mi = 4; mi < 8; ++mi)
      a[mi] = *(const bf16x8*)&a0[(wr * 128 + mi * 16 + fr) * 32 + fo * 8];
    if (st) STAGE_B(kt + 2, b2);
    __builtin_amdgcn_s_barrier();
    asm volatile("s_waitcnt lgkmcnt(0)" ::: "memory");
    __builtin_amdgcn_sched_barrier(0);
    __builtin_amdgcn_s_setprio(1);
#pragma unroll
    for (int mi = 4; mi < 8; ++mi)
#pragma unroll
      for (int ni = 0; ni < 4; ++ni)
        acc[mi][ni] = __builtin_amdgcn_mfma_f32_16x16x32_bf16(a[mi], b[ni], acc[mi][ni], 0, 0, 0);
    __builtin_amdgcn_s_setprio(0);
    if (kt < 31) {                                    // validate tile kt+1 before next iter
      if (st) asm volatile("s_waitcnt vmcnt(4)" ::: "memory");
      else    asm volatile("s_waitcnt vmcnt(0)" ::: "memory");
      __builtin_amdgcn_sched_barrier(0);
    }
    __builtin_amdgcn_s_barrier();                     // also gates reuse of a0/b0 by kt+1's STAGE target

    u16* t;
    t = a0; a0 = a1; a1 = a2; a2 = t;
    t = b0; b0 = b1; b1 = b2; b2 = t;
  }

  // ---- epilogue: per-wave LDS bounce for contiguous stores ----
  __syncthreads();                                    // all waves done with LDS tiles
  if (OUT_BF16) {
    u16* bw = (u16*)&As[0] + wave * 2048;             // 4KB region per wave (uses 32KB)
#pragma unroll
    for (int mi = 0; mi < 8; ++mi) {
#pragma unroll
      for (int ni = 0; ni < 4; ++ni) {
        float bv = bias[n0 + wc * 64 + ni * 16 + fr];
#pragma unroll
        for (int r = 0; r < 4; ++r)
          bw[(fo * 4 + r) * 64 + ni * 16 + fr] = f2bf(acc[mi][ni][r] + bv);
      }
      int lane = tid & 63;
      int ro = lane >> 2, ch = lane & 3;
      int m = m0 + wr * 128 + mi * 16 + ro;
      bf16x8 v0 = *(const bf16x8*)&bw[ro * 64 + ch * 16];
      bf16x8 v1 = *(const bf16x8*)&bw[ro * 64 + ch * 16 + 8];
      if (m < M) {
        u16* dst = (u16*)Cout + (size_t)m * 1024 + n0 + wc * 64 + ch * 16;
        *(bf16x8*)dst = v0;
        *(bf16x8*)(dst + 8) = v1;
      }
    }
  } else {
    float* fw = (float*)&As[0] + wave * 1024;         // 4KB region per wave
#pragma unroll
    for (int mi = 0; mi < 8; ++mi) {
#pragma unroll
      for (int ni = 0; ni < 4; ++ni) {
        float bv = bias[n0 + wc * 64 + ni * 16 + fr];
#pragma unroll
        for (int r = 0; r < 4; ++r)
          fw[(fo * 4 + r) * 64 + ni * 16 + fr] = acc[mi][ni][r] + bv;
      }
      int lane = tid & 63;
      int ro = lane >> 2, ch = lane & 3;
      int m = m0 + wr * 128 + mi * 16 + ro;
      f32x4 v0 = *(const f32x4*)&fw[ro * 64 + ch * 16];
      f32x4 v1 = *(const f32x4*)&fw[ro * 64 + ch * 16 + 4];
      f32x4 v2 = *(const f32x4*)&fw[ro * 64 + ch * 16 + 8];
      f32x4 v3 = *(const f32x4*)&fw[ro * 64 + ch * 16 + 12];
      if (m < M) {
        float* dst = (float*)Cout + (size_t)m * 1024 + n0 + wc * 64 + ch * 16;
        *(f32x4*)dst = v0;
        *(f32x4*)(dst + 4) = v1;
        *(f32x4*)(dst + 8) = v2;
        *(f32x4*)(dst + 12) = v3;
      }
    }
  }
}

// ---------------- rope Q + [B*S][H] -> [B][NH][S][HD]; 2 outputs/thread ----------------
__global__ __launch_bounds__(256) void rope_q(const u16* __restrict__ P,
                                              const float* __restrict__ tab,
                                              u16* __restrict__ R) {
  int idx = blockIdx.x * 256 + threadIdx.x;   // 8,192,000 = 512 bh * 500 s * 32 j
  int j = idx & 31;
  int t = idx >> 5;
  int s = t % 500;
  int bh = t / 500;
  int h = bh & 15, b = bh >> 4;
  size_t src = (size_t)(b * 500 + s) * 1024 + h * 64;
  float x0 = bf2f(P[src + j]);
  float x1 = bf2f(P[src + 32 + j]);
  float xe = bf2f(P[src + 2 * j]);
  float xo = bf2f(P[src + 2 * j + 1]);
  f32x2 cn = *(const f32x2*)(tab + (s * 32 + j) * 2);
  size_t dst = (size_t)t * 64;
  R[dst + j]      = f2bf(x0 * cn[0] - xo * cn[1]);   // d<32
  R[dst + 32 + j] = f2bf(x1 * cn[0] + xe * cn[1]);   // d>=32
}

// ---------------- K: rope + gather kept tokens -> pre-swizzled tiles [bh][tile][64][128B] ------
__global__ __launch_bounds__(256) void gather_k(const u16* __restrict__ Pk,
                                                const float* __restrict__ tab,
                                                const u16* __restrict__ karr,
                                                const int* __restrict__ kept,
                                                u16* __restrict__ Ktg) {
  const int tile = blockIdx.x;
  const int bh = blockIdx.y;
  const int h = bh & 15, b = bh >> 4;
  if (tile * 64 >= kept[b]) return;
  char* out = (char*)(Ktg + ((size_t)bh * 8 + tile) * 4096);
  const int tid = threadIdx.x;
#pragma unroll
  for (int i = 0; i < 8; ++i) {
    int item = i * 256 + tid;            // 2048 = 64 rows * 32 j
    int row = item >> 5, j = item & 31;
    int tok = karr[b * 512 + tile * 64 + row];
    int sw = (row & 7) << 4;
    u16 o0 = 0, o1 = 0;
    if (tok != 0xFFFF) {
      const u16* src = Pk + ((size_t)b * 500 + tok) * 1024 + h * 64;
      float x0 = bf2f(src[j]);
      float x1 = bf2f(src[32 + j]);
      float xe = bf2f(src[2 * j]);
      float xo = bf2f(src[2 * j + 1]);
      f32x2 cn = *(const f32x2*)(tab + (tok * 32 + j) * 2);
      o0 = f2bf(x0 * cn[0] - xo * cn[1]);
      o1 = f2bf(x1 * cn[0] + xe * cn[1]);
    }
    *(u16*)(out + row * 128 + ((2 * j) ^ sw)) = o0;
    *(u16*)(out + row * 128 + ((64 + 2 * j) ^ sw)) = o1;
  }
}

// ---------------- V: gather + transpose -> pre-swizzled V^T tiles [bh][tile][64 d][128B] ------
__global__ __launch_bounds__(256) void gather_v(const u16* __restrict__ Pv,
                                                const u16* __restrict__ karr,
                                                const int* __restrict__ kept,
                                                u16* __restrict__ Vtg) {
  const int tile = blockIdx.x;
  const int bh = blockIdx.y;
  const int h = bh & 15, b = bh >> 4;
  if (tile * 64 >= kept[b]) return;
  const int tid = threadIdx.x;
  __shared__ __attribute__((aligned(16))) u16 Vl[64 * 64];
#pragma unroll
  for (int i = 0; i < 2; ++i) {
    int chunk = i * 256 + tid;           // 512: slot(64) x seg(8)
    int slot = chunk >> 3, seg = chunk & 7;
    int tok = karr[b * 512 + tile * 64 + slot];
    bf16x8 v;
#pragma unroll
    for (int p = 0; p < 8; ++p) v[p] = 0;
    if (tok != 0xFFFF)
      v = *(const bf16x8*)(Pv + ((size_t)b * 500 + tok) * 1024 + h * 64 + seg * 8);
    *(bf16x8*)&Vl[slot * 64 + seg * 8] = v;
  }
  __syncthreads();
  u16* out = Vtg + ((size_t)bh * 8 + tile) * 4096;
#pragma unroll
  for (int i = 0; i < 2; ++i) {
    int chunk = i * 256 + tid;           // d(64) x c16(8)
    int d = chunk >> 3, c16 = chunk & 7;
    int k0 = ((c16 * 16) ^ ((d & 7) << 4)) >> 1;
    bf16x8 v;
#pragma unroll
    for (int p = 0; p < 8; ++p) v[p] = (short)Vl[(k0 + p) * 64 + d];
    *(bf16x8*)(out + chunk * 8) = v;
  }
}

// ---------------- flash attention: compressed k, swapped QK^T, in-reg softmax ----------------
__global__ __launch_bounds__(512) void attn_kernel(const u16* __restrict__ Qr,
                                                   const u16* __restrict__ Ktg,
                                                   const u16* __restrict__ Vtg,
                                                   const float* __restrict__ rel_emb,
                                                   const u16* __restrict__ karr,
                                                   const int* __restrict__ kept,
                                                   u16* __restrict__ AO) {
  const int bid = blockIdx.x;
  const int bh = ((bid >> 5) << 3) | (bid & 7);
  const int qb = (bid >> 3) & 3;
  const int h = bh & 15, b = bh >> 4;
  const int q0 = qb * 128;
  const int tid = threadIdx.x;
  const int wave = tid >> 6;
  const int fr = tid & 15, fo = (tid >> 4) & 3;

  __shared__ __attribute__((aligned(16))) u16 Ks[2][4096];
  __shared__ __attribute__((aligned(16))) u16 Vs[2][4096];
  __shared__ __attribute__((aligned(16))) u16 Pl[8][1024];
  __shared__ float rel2[640];
  __shared__ u16 okk[512];

  const int nk = kept[b];
  const int nt = (nk + 63) >> 6;
  const float LOG2E = 1.44269504f;
  for (int i = tid; i < 640; i += 512) {
    int g = min(max(q0 - 12 + i, 0), 998);
    rel2[i] = rel_emb[g * 16 + h] * LOG2E;
  }
  okk[tid] = karr[b * 512 + tid];

  const int qloc = wave * 16 + fr;
  const int qg = q0 + qloc;
  const bool qok = (qg < 500);
  const u16* Qb = Qr + ((size_t)bh * 500 + min(qg, 499)) * 64;
  bf16x8 qf0 = *(const bf16x8*)(Qb + fo * 8);
  bf16x8 qf1 = *(const bf16x8*)(Qb + 32 + fo * 8);

  f32x4 o[4];
#pragma unroll
  for (int nf = 0; nf < 4; ++nf)
#pragma unroll
    for (int j = 0; j < 4; ++j) o[nf][j] = 0.f;
  float mrun = -1e30f, lrun = 0.f;

  const u16* Kb = Ktg + (size_t)bh * 32768;
  const u16* Vb = Vtg + (size_t)bh * 32768;
  const int sw = (fr & 7) << 4;
  const float SC = 0.18033688f;          // 0.125 * log2(e)

  if (nt > 0) {
    async16(&Ks[0][tid * 8], Kb + tid * 8);
    async16(&Vs[0][tid * 8], Vb + tid * 8);
  }
  __syncthreads();

  for (int t = 0; t < nt; ++t) {
    const int cur = t & 1;
    if (t + 1 < nt) {
      async16(&Ks[cur ^ 1][tid * 8], Kb + (t + 1) * 4096 + tid * 8);
      async16(&Vs[cur ^ 1][tid * 8], Vb + (t + 1) * 4096 + tid * 8);
    }
    const char* Kt = (const char*)(cur ? &Ks[1][0] : &Ks[0][0]);
    const char* Vt = (const char*)(cur ? &Vs[1][0] : &Vs[0][0]);

    f32x4 sacc[4];
    __builtin_amdgcn_s_setprio(1);
#pragma unroll
    for (int nf = 0; nf < 4; ++nf) {
#pragma unroll
      for (int jj = 0; jj < 4; ++jj) sacc[nf][jj] = 0.f;
      int rb = (nf * 16 + fr) * 128;
      bf16x8 kb0 = *(const bf16x8*)(Kt + rb + ((fo * 16) ^ sw));
      bf16x8 kb1 = *(const bf16x8*)(Kt + rb + ((64 + fo * 16) ^ sw));
      sacc[nf] = __builtin_amdgcn_mfma_f32_16x16x32_bf16(kb0, qf0, sacc[nf], 0, 0, 0);
      sacc[nf] = __builtin_amdgcn_mfma_f32_16x16x32_bf16(kb1, qf1, sacc[nf], 0, 0, 0);
    }
    __builtin_amdgcn_s_setprio(0);

    float p2[4][4];
    float pmax = -1e30f;
#pragma unroll
    for (int nf = 0; nf < 4; ++nf) {
#pragma unroll
      for (int r = 0; r < 4; ++r) {
        int slot = t * 64 + nf * 16 + fo * 4 + r;
        int ok = okk[slot];
        float rv = rel2[min(max(qloc - ok + 511, 0), 639)];
        bool valid = (ok != 0xFFFF) && qok;
        float s2 = valid ? fmaf(sacc[nf][r], SC, rv) : -1e30f;
        p2[nf][r] = s2;
        pmax = fmaxf(pmax, s2);
      }
    }
    pmax = fmaxf(pmax, __shfl_xor(pmax, 16, 64));
    pmax = fmaxf(pmax, __shfl_xor(pmax, 32, 64));

    if (!__all(pmax <= mrun + 8.0f)) {   // defer-max (T13)
      float mnew = fmaxf(mrun, pmax);
      float scl = EXP2(mrun - mnew);
      lrun *= scl;
#pragma unroll
      for (int nf = 0; nf < 4; ++nf)
#pragma unroll
        for (int r = 0; r < 4; ++r) o[nf][r] *= scl;
      mrun = mnew;
    }

    float lsum = 0.f;
#pragma unroll
    for (int nf = 0; nf < 4; ++nf) {
      float e0 = EXP2(p2[nf][0] - mrun);
      float e1 = EXP2(p2[nf][1] - mrun);
      float e2 = EXP2(p2[nf][2] - mrun);
      float e3 = EXP2(p2[nf][3] - mrun);
      lsum += (e0 + e1) + (e2 + e3);
      uint2 w; w.x = packbf(e0, e1); w.y = packbf(e2, e3);
      *(uint2*)((char*)&Pl[wave][0] + fr * 128 + ((nf * 32 + fo * 8) ^ sw)) = w;
    }
    lsum += __shfl_xor(lsum, 16, 64);
    lsum += __shfl_xor(lsum, 32, 64);
    lrun += lsum;

    bf16x8 pa0 = *(const bf16x8*)((char*)&Pl[wave][0] + fr * 128 + ((fo * 16) ^ sw));
    bf16x8 pa1 = *(const bf16x8*)((char*)&Pl[wave][0] + fr * 128 + ((64 + fo * 16) ^ sw));
    __builtin_amdgcn_s_setprio(1);
#pragma unroll
    for (int nf = 0; nf < 4; ++nf) {
      int rb = (nf * 16 + fr) * 128;
      bf16x8 vb0 = *(const bf16x8*)(Vt + rb + ((fo * 16) ^ sw));
      bf16x8 vb1 = *(const bf16x8*)(Vt + rb + ((64 + fo * 16) ^ sw));
      o[nf] = __builtin_amdgcn_mfma_f32_16x16x32_bf16(vb0, pa0, o[nf], 0, 0, 0);
      o[nf] = __builtin_amdgcn_mfma_f32_16x16x32_bf16(vb1, pa1, o[nf], 0, 0, 0);
    }
    __builtin_amdgcn_s_setprio(0);
    __syncthreads();
  }

  float inv = (lrun > 0.f) ? 1.f / lrun : 0.f;
#pragma unroll
  for (int nf = 0; nf < 4; ++nf) {
    float v0 = fminf(fmaxf(o[nf][0] * inv, -30.f), 30.f);
    float v1 = fminf(fmaxf(o[nf][1] * inv, -30.f), 30.f);
    float v2 = fminf(fmaxf(o[nf][2] * inv, -30.f), 30.f);
    float v3 = fminf(fmaxf(o[nf][3] * inv, -30.f), 30.f);
    uint2 w; w.x = packbf(v0, v1); w.y = packbf(v2, v3);
    *(uint2*)((char*)&Pl[wave][0] + fr * 128 + ((nf * 32 + fo * 8) ^ sw)) = w;
  }
  {
    int lane = tid & 63;
    int ro = lane >> 2, c = lane & 3;
    int swr = (ro & 7) << 4;
    const char* Pw = (const char*)&Pl[wave][0];
    bf16x8 v0 = *(const bf16x8*)(Pw + ro * 128 + ((c * 32) ^ swr));
    bf16x8 v1 = *(const bf16x8*)(Pw + ro * 128 + ((c * 32 + 16) ^ swr));
    int token = q0 + wave * 16 + ro;
    if (token < 500) {
      u16* dst = AO + (size_t)(b * 500 + token) * 1024 + h * 64 + c * 16;
      *(bf16x8*)dst = v0;
      *(bf16x8*)(dst + 8) = v1;
    }
  }
}

// ---------------- launch ----------------
extern "C" void kernel_launch(void* const* d_in, const int* in_sizes, int n_in,
                              void* d_out, int out_size, void* d_ws, size_t ws_size,
                              hipStream_t stream) {
  const float* query = (const float*)d_in[0];
  const float* key_  = (const float*)d_in[1];
  const float* value = (const float*)d_in[2];
  const void*  mask  = d_in[3];
  const float* Wq = (const float*)d_in[4];
  const float* bq = (const float*)d_in[5];
  const float* Wk = (const float*)d_in[6];
  const float* bk = (const float*)d_in[7];
  const float* Wv = (const float*)d_in[8];
  const float* bv = (const float*)d_in[9];
  const float* Wo = (const float*)d_in[10];
  const float* bo = (const float*)d_in[11];
  const float* rel = (const float*)d_in[12];

  // ws map: Wb 8.39MB | 4 slots x 32MiB | misc ~0.26MB
  // slot liveness: A: Xq->Pk->Vtg | B: Xk->Qro | C: Xv->Pq->Ktg | D: Pv->AO
  char* ws = (char*)d_ws;
  const size_t SLOT = 33554432;
  u16* Wb = (u16*)ws;
  char* Aq = ws + 8388608;
  char* Bq = Aq + SLOT;
  char* Cq = Bq + SLOT;
  char* Dq = Cq + SLOT;
  char* MISC = Dq + SLOT;
  u8*  maskb = (u8*)MISC;
  u16* karr  = (u16*)(MISC + 65536);
  int* kept  = (int*)(MISC + 131072);
  float* tab = (float*)(MISC + 131584);

  mask_prep<<<1, 256, 0, stream>>>(mask, maskb);
  build_gather<<<32, 512, 0, stream>>>(maskb, karr, kept);
  rope_table<<<63, 256, 0, stream>>>(tab);

  cvt_f32_bf16<<<512, 256, 0, stream>>>(Wq, Wb + 0 * 1048576, 262144);
  cvt_f32_bf16<<<512, 256, 0, stream>>>(Wk, Wb + 1 * 1048576, 262144);
  cvt_f32_bf16<<<512, 256, 0, stream>>>(Wv, Wb + 2 * 1048576, 262144);
  cvt_f32_bf16<<<512, 256, 0, stream>>>(Wo, Wb + 3 * 1048576, 262144);
  cvt_f32_bf16<<<2048, 256, 0, stream>>>(query, (u16*)Aq, 4096000);
  cvt_f32_bf16<<<2048, 256, 0, stream>>>(key_,  (u16*)Bq, 4096000);
  cvt_f32_bf16<<<2048, 256, 0, stream>>>(value, (u16*)Cq, 4096000);

  gemm_bt<true><<<252, 512, 0, stream>>>((u16*)Cq, Wb + 2 * 1048576, bv, Dq, 16000);  // Pv=D
  gemm_bt<true><<<252, 512, 0, stream>>>((u16*)Aq, Wb + 0 * 1048576, bq, Cq, 16000);  // Pq=C
  gemm_bt<true><<<252, 512, 0, stream>>>((u16*)Bq, Wb + 1 * 1048576, bk, Aq, 16000);  // Pk=A

  rope_q<<<32000, 256, 0, stream>>>((u16*)Cq, tab, (u16*)Bq);                   // Qro=B
  gather_k<<<dim3(8, 512), 256, 0, stream>>>((u16*)Aq, tab, karr, kept, (u16*)Cq);  // Ktg=C
  gather_v<<<dim3(8, 512), 256, 0, stream>>>((u16*)Dq, karr, kept, (u16*)Aq);       // Vtg=A

  attn_kernel<<<2048, 512, 0, stream>>>((u16*)Bq, (u16*)Cq, (u16*)Aq, rel,
                                        karr, kept, (u16*)Dq);                  // AO=D

  gemm_bt<false><<<252, 512, 0, stream>>>((u16*)Dq, Wb + 3 * 1048576, bo, (float*)d_out, 16000);
}

// Round 9
// 382.542 us; speedup vs baseline: 1.2070x; 1.0121x over previous
//
#include <hip/hip_runtime.h>
#include <math.h>

// FlashMultiHeadAttention: B=32 S=500 H=1024 NH=16 HD=64, rope + rel-pos-bias + key-pad mask.
// Pipeline: [mask->bytes] [gather-list scan] [rope table] [f32->bf16 cvt]
//           [QKV proj GEMM 256x256 8-wave, fine-phase counted-vmcnt, XOR-swizzled LDS]
//           [rope Q] [rope+gather+swizzle K tiles] [gather+transpose+swizzle V tiles]
//           [flash attn: masked-k compressed, swapped QK^T, in-reg softmax] [out proj GEMM]

typedef unsigned short u16;
typedef unsigned int   u32;
typedef unsigned char  u8;
using bf16x8 = __attribute__((ext_vector_type(8))) short;
using f32x4  = __attribute__((ext_vector_type(4))) float;
using f32x2  = __attribute__((ext_vector_type(2))) float;
using u16x4  = __attribute__((ext_vector_type(4))) unsigned short;

#define DEV __device__ __forceinline__

#if __has_builtin(__builtin_amdgcn_exp2f)
#define EXP2(x) __builtin_amdgcn_exp2f(x)
#else
#define EXP2(x) exp2f(x)
#endif

DEV u16 f2bf(float f) {                 // RNE f32 -> bf16
  union { float f; u32 u; } c; c.f = f;
  u32 u = c.u;
  return (u16)((u + 0x7FFFu + ((u >> 16) & 1u)) >> 16);
}
DEV float bf2f(u16 h) {
  union { u32 u; float f; } c; c.u = ((u32)h) << 16;
  return c.f;
}
DEV u32 packbf(float a, float b) {      // half-up rounding, packed pair
  union { float f; u32 u; } x, y; x.f = a; y.f = b;
  return ((x.u + 0x8000u) >> 16) | ((y.u + 0x8000u) & 0xFFFF0000u);
}

// async global->LDS, 16B/lane; LDS dest = wave-uniform base + lane*16 (linear).
DEV void async16(void* l, const void* g) {
  __builtin_amdgcn_global_load_lds(
      (__attribute__((address_space(1))) unsigned int*)g,
      (__attribute__((address_space(3))) unsigned int*)l, 16, 0, 0);
}

// ---------------- mask prep: detect bool storage (i32/f32/u8), emit bytes ----------------
__global__ __launch_bounds__(256) void mask_prep(const void* __restrict__ mraw,
                                                 u8* __restrict__ maskb) {
  __shared__ int bad_i32, bad_f32;
  if (threadIdx.x == 0) { bad_i32 = 0; bad_f32 = 0; }
  __syncthreads();
  const u32* w = (const u32*)mraw;
  int li = 0, lf = 0;
  for (int g = threadIdx.x; g < 4000; g += 256) {
    u32 v = w[g];
    li |= !(v == 0u || v == 1u);
    lf |= !(v == 0u || v == 0x3F800000u);
  }
  if (li) atomicOr(&bad_i32, 1);
  if (lf) atomicOr(&bad_f32, 1);
  __syncthreads();
  int mode = (!bad_i32) ? 0 : ((!bad_f32) ? 1 : 2);   // 0=int32, 1=float32, 2=uint8
  for (int i = threadIdx.x; i < 16000; i += 256) {
    int v;
    if (mode == 0)      v = ((const int*)mraw)[i] != 0;
    else if (mode == 1) v = (((const float*)mraw)[i] != 0.0f);
    else                v = ((const u8*)mraw)[i] != 0;
    maskb[i] = (u8)v;
  }
}

// ---------------- per-batch gather list: karr[b][512] = kept token or 0xFFFF ----------------
__global__ __launch_bounds__(512) void build_gather(const u8* __restrict__ maskb,
                                                    u16* __restrict__ karr,
                                                    int* __restrict__ kept) {
  const int b = blockIdx.x;
  const int t = threadIdx.x;
  const int lane = t & 63, wave = t >> 6;
  __shared__ int wbase[8];
  __shared__ int wpop[8];
  int v = (t < 500) ? (int)maskb[b * 500 + t] : 0;
  unsigned long long bal = __ballot(v != 0);
  karr[b * 512 + t] = 0xFFFF;
  if (lane == 0) wpop[wave] = __popcll(bal);
  __syncthreads();
  if (t == 0) {
    int s = 0;
    for (int w = 0; w < 8; ++w) { wbase[w] = s; s += wpop[w]; }
    kept[b] = s;
  }
  __syncthreads();
  if (v) {
    int rank = wbase[wave] + __popcll(bal & ((1ull << lane) - 1ull));
    karr[b * 512 + rank] = (u16)t;
  }
}

// ---------------- rope cos/sin table: tab[(s*32+j)*2] = cos, +1 = sin ----------------
__global__ __launch_bounds__(256) void rope_table(float* __restrict__ tab) {
  int idx = blockIdx.x * 256 + threadIdx.x;
  if (idx >= 16000) return;
  int s = idx >> 5, j = idx & 31;
  float ang = (float)s * exp2f(-(float)j * 0.41524100f);  // 10000^(-j/32)
  float sn, cs;
  sincosf(ang, &sn, &cs);
  tab[idx * 2] = cs;
  tab[idx * 2 + 1] = sn;
}

// ---------------- f32 -> bf16 convert (vectorized) ----------------
__global__ __launch_bounds__(256) void cvt_f32_bf16(const float* __restrict__ src,
                                                    u16* __restrict__ dst, int n4) {
  int i = blockIdx.x * 256 + threadIdx.x;
  int stride = gridDim.x * 256;
  for (; i < n4; i += stride) {
    f32x4 f = *(const f32x4*)(src + (size_t)i * 4);
    u16x4 o;
    o[0] = f2bf(f[0]); o[1] = f2bf(f[1]); o[2] = f2bf(f[2]); o[3] = f2bf(f[3]);
    *(u16x4*)(dst + (size_t)i * 4) = o;
  }
}

// ---------------- GEMM: C[m][n] = sum_k A[m][k]*Bw[n][k] + bias[n] ----------------
// 256x256 tile, BK=32, 512 thr / 8 waves (2x4), per-wave 128x64.
// LDS tiles packed as 128B rows (2 m-rows per LDS row) with XOR swizzle:
//   element (m, fo-chunk) lives at LDS row m>>1, 16B-slot (4*(m&1)+fo) ^ ((m>>1)&7).
// Staged via inverse-swizzled GLOBAL source + linear gload_lds dest (G21);
// ds_read uses the same XOR -> 2-way (free) bank access per beat.
// Fine-phase schedule: 2 phases/K-step, counted vmcnt (never 0 mid-loop), 3 buffers.
template <bool OUT_BF16>
__global__ __launch_bounds__(512, 2) void gemm_bt(const u16* __restrict__ A,
                                                  const u16* __restrict__ Bw,
                                                  const float* __restrict__ bias,
                                                  void* __restrict__ Cout, int M) {
  const int bid = blockIdx.x;
  const int xcd = bid & 7, idx = bid >> 3;            // dispatch round-robins XCDs
  const int swz = (xcd < 4 ? xcd * 32 : 128 + (xcd - 4) * 31) + idx;  // 252 = 4*32+4*31
  const int m0 = (swz >> 2) * 256;                    // consecutive swz share A panel
  const int n0 = (swz & 3) * 256;
  const int tid = threadIdx.x;
  const int wave = tid >> 6;
  const int wr = wave >> 2, wc = wave & 3;
  const int fr = tid & 15, fo = (tid >> 4) & 3;
  const int fr2 = fr >> 1;
  const int aslot = ((4 * (fr & 1) + fo) ^ fr2) * 8;  // u16 offset within 64-u16 LDS row

  const int TILE = 256 * 32;                          // u16 elems per buffer (16KB)
  __shared__ __attribute__((aligned(16))) u16 As[3 * 256 * 32];   // 48KB
  __shared__ __attribute__((aligned(16))) u16 Bs[3 * 256 * 32];   // 48KB

  f32x4 acc[8][4];
#pragma unroll
  for (int mi = 0; mi < 8; ++mi)
#pragma unroll
    for (int ni = 0; ni < 4; ++ni)
#pragma unroll
      for (int j = 0; j < 4; ++j) acc[mi][ni][j] = 0.f;

  // staging: LDS chunk c (16B) -> row r=c>>3, slot s=c&7; v = s ^ (r&7);
  // source element: m = 2r + (v>>2), k-chunk = v&3.
  auto STAGE_A = [&](int kt2, u16* sA) {
#pragma unroll
    for (int i = 0; i < 2; ++i) {
      int c = i * 512 + tid;
      int r = c >> 3, v = (c & 7) ^ (r & 7);
      int ar = min(m0 + 2 * r + (v >> 2), M - 1);
      async16(&sA[c * 8], A + (size_t)ar * 1024 + kt2 * 32 + (v & 3) * 8);
    }
  };
  auto STAGE_B = [&](int kt2, u16* sB) {
#pragma unroll
    for (int i = 0; i < 2; ++i) {
      int c = i * 512 + tid;
      int r = c >> 3, v = (c & 7) ^ (r & 7);
      int nr = n0 + 2 * r + (v >> 2);
      async16(&sB[c * 8], Bw + (size_t)nr * 1024 + kt2 * 32 + (v & 3) * 8);
    }
  };

  u16 *a0 = &As[0], *a1 = &As[TILE], *a2 = &As[2 * TILE];
  u16 *b0 = &Bs[0], *b1 = &Bs[TILE], *b2 = &Bs[2 * TILE];
  STAGE_A(0, a0); STAGE_B(0, b0);                     // 4 vmem instrs (tile 0)
  STAGE_A(1, a1); STAGE_B(1, b1);                     // 4 more (tile 1)
  asm volatile("s_waitcnt vmcnt(4)" ::: "memory");    // tile 0 landed; tile 1 in flight
  __builtin_amdgcn_sched_barrier(0);
  __builtin_amdgcn_s_barrier();

  for (int kt = 0; kt < 32; ++kt) {
    const bool st = (kt + 2 < 32);
    // ---- phase 0: frags m0-3 + all b; stage A of kt+2 ----
    bf16x8 a[8], b[4];
#pragma unroll
    for (int mi = 0; mi < 4; ++mi)
      a[mi] = *(const bf16x8*)&a0[(wr * 64 + mi * 8 + fr2) * 64 + aslot];
#pragma unroll
    for (int ni = 0; ni < 4; ++ni)
      b[ni] = *(const bf16x8*)&b0[(wc * 32 + ni * 8 + fr2) * 64 + aslot];
    if (st) STAGE_A(kt + 2, a2);
    __builtin_amdgcn_s_barrier();
    asm volatile("s_waitcnt lgkmcnt(0)" ::: "memory");
    __builtin_amdgcn_sched_barrier(0);
    __builtin_amdgcn_s_setprio(1);
#pragma unroll
    for (int mi = 0; mi < 4; ++mi)
#pragma unroll
      for (int ni = 0; ni < 4; ++ni)
        acc[mi][ni] = __builtin_amdgcn_mfma_f32_16x16x32_bf16(a[mi], b[ni], acc[mi][ni], 0, 0, 0);
    __builtin_amdgcn_s_setprio(0);
    __builtin_amdgcn_s_barrier();

    // ---- phase 1: frags m4-7; stage B of kt+2 ----
#pragma unroll
    for (int mi = 4; mi < 8; ++mi)
      a[mi] = *(const bf16x8*)&a0[(wr * 64 + mi * 8 + fr2) * 64 + aslot];
    if (st) STAGE_B(kt + 2, b2);
    __builtin_amdgcn_s_barrier();
    asm volatile("s_waitcnt lgkmcnt(0)" ::: "memory");
    __builtin_amdgcn_sched_barrier(0);
    __builtin_amdgcn_s_setprio(1);
#pragma unroll
    for (int mi = 4; mi < 8; ++mi)
#pragma unroll
      for (int ni = 0; ni < 4; ++ni)
        acc[mi][ni] = __builtin_amdgcn_mfma_f32_16x16x32_bf16(a[mi], b[ni], acc[mi][ni], 0, 0, 0);
    __builtin_amdgcn_s_setprio(0);
    if (kt < 31) {                                    // validate tile kt+1 before next iter
      if (st) asm volatile("s_waitcnt vmcnt(4)" ::: "memory");
      else    asm volatile("s_waitcnt vmcnt(0)" ::: "memory");
      __builtin_amdgcn_sched_barrier(0);
    }
    __builtin_amdgcn_s_barrier();                     // gates reuse of a0/b0 by next STAGE

    u16* t;
    t = a0; a0 = a1; a1 = a2; a2 = t;
    t = b0; b0 = b1; b1 = b2; b2 = t;
  }

  // ---- epilogue: per-wave LDS bounce for contiguous stores ----
  __syncthreads();                                    // all waves done with LDS tiles
  if (OUT_BF16) {
    u16* bw = (u16*)&As[0] + wave * 2048;             // 4KB region per wave
#pragma unroll
    for (int mi = 0; mi < 8; ++mi) {
#pragma unroll
      for (int ni = 0; ni < 4; ++ni) {
        float bv = bias[n0 + wc * 64 + ni * 16 + fr];
#pragma unroll
        for (int r = 0; r < 4; ++r)
          bw[(fo * 4 + r) * 64 + ni * 16 + fr] = f2bf(acc[mi][ni][r] + bv);
      }
      int lane = tid & 63;
      int ro = lane >> 2, ch = lane & 3;
      int m = m0 + wr * 128 + mi * 16 + ro;
      bf16x8 v0 = *(const bf16x8*)&bw[ro * 64 + ch * 16];
      bf16x8 v1 = *(const bf16x8*)&bw[ro * 64 + ch * 16 + 8];
      if (m < M) {
        u16* dst = (u16*)Cout + (size_t)m * 1024 + n0 + wc * 64 + ch * 16;
        *(bf16x8*)dst = v0;
        *(bf16x8*)(dst + 8) = v1;
      }
    }
  } else {
    float* fw = (float*)&As[0] + wave * 1024;         // 4KB region per wave
#pragma unroll
    for (int mi = 0; mi < 8; ++mi) {
#pragma unroll
      for (int ni = 0; ni < 4; ++ni) {
        float bv = bias[n0 + wc * 64 + ni * 16 + fr];
#pragma unroll
        for (int r = 0; r < 4; ++r)
          fw[(fo * 4 + r) * 64 + ni * 16 + fr] = acc[mi][ni][r] + bv;
      }
      int lane = tid & 63;
      int ro = lane >> 2, ch = lane & 3;
      int m = m0 + wr * 128 + mi * 16 + ro;
      f32x4 v0 = *(const f32x4*)&fw[ro * 64 + ch * 16];
      f32x4 v1 = *(const f32x4*)&fw[ro * 64 + ch * 16 + 4];
      f32x4 v2 = *(const f32x4*)&fw[ro * 64 + ch * 16 + 8];
      f32x4 v3 = *(const f32x4*)&fw[ro * 64 + ch * 16 + 12];
      if (m < M) {
        float* dst = (float*)Cout + (size_t)m * 1024 + n0 + wc * 64 + ch * 16;
        *(f32x4*)dst = v0;
        *(f32x4*)(dst + 4) = v1;
        *(f32x4*)(dst + 8) = v2;
        *(f32x4*)(dst + 12) = v3;
      }
    }
  }
}

// ---------------- rope Q + [B*S][H] -> [B][NH][S][HD]; 2 outputs/thread ----------------
__global__ __launch_bounds__(256) void rope_q(const u16* __restrict__ P,
                                              const float* __restrict__ tab,
                                              u16* __restrict__ R) {
  int idx = blockIdx.x * 256 + threadIdx.x;   // 8,192,000 = 512 bh * 500 s * 32 j
  int j = idx & 31;
  int t = idx >> 5;
  int s = t % 500;
  int bh = t / 500;
  int h = bh & 15, b = bh >> 4;
  size_t src = (size_t)(b * 500 + s) * 1024 + h * 64;
  float x0 = bf2f(P[src + j]);
  float x1 = bf2f(P[src + 32 + j]);
  float xe = bf2f(P[src + 2 * j]);
  float xo = bf2f(P[src + 2 * j + 1]);
  f32x2 cn = *(const f32x2*)(tab + (s * 32 + j) * 2);
  size_t dst = (size_t)t * 64;
  R[dst + j]      = f2bf(x0 * cn[0] - xo * cn[1]);   // d<32
  R[dst + 32 + j] = f2bf(x1 * cn[0] + xe * cn[1]);   // d>=32
}

// ---------------- K: rope + gather kept tokens -> pre-swizzled tiles [bh][tile][64][128B] ------
__global__ __launch_bounds__(256) void gather_k(const u16* __restrict__ Pk,
                                                const float* __restrict__ tab,
                                                const u16* __restrict__ karr,
                                                const int* __restrict__ kept,
                                                u16* __restrict__ Ktg) {
  const int tile = blockIdx.x;
  const int bh = blockIdx.y;
  const int h = bh & 15, b = bh >> 4;
  if (tile * 64 >= kept[b]) return;
  char* out = (char*)(Ktg + ((size_t)bh * 8 + tile) * 4096);
  const int tid = threadIdx.x;
#pragma unroll
  for (int i = 0; i < 8; ++i) {
    int item = i * 256 + tid;            // 2048 = 64 rows * 32 j
    int row = item >> 5, j = item & 31;
    int tok = karr[b * 512 + tile * 64 + row];
    int sw = (row & 7) << 4;
    u16 o0 = 0, o1 = 0;
    if (tok != 0xFFFF) {
      const u16* src = Pk + ((size_t)b * 500 + tok) * 1024 + h * 64;
      float x0 = bf2f(src[j]);
      float x1 = bf2f(src[32 + j]);
      float xe = bf2f(src[2 * j]);
      float xo = bf2f(src[2 * j + 1]);
      f32x2 cn = *(const f32x2*)(tab + (tok * 32 + j) * 2);
      o0 = f2bf(x0 * cn[0] - xo * cn[1]);
      o1 = f2bf(x1 * cn[0] + xe * cn[1]);
    }
    *(u16*)(out + row * 128 + ((2 * j) ^ sw)) = o0;
    *(u16*)(out + row * 128 + ((64 + 2 * j) ^ sw)) = o1;
  }
}

// ---------------- V: gather + transpose -> pre-swizzled V^T tiles [bh][tile][64 d][128B] ------
__global__ __launch_bounds__(256) void gather_v(const u16* __restrict__ Pv,
                                                const u16* __restrict__ karr,
                                                const int* __restrict__ kept,
                                                u16* __restrict__ Vtg) {
  const int tile = blockIdx.x;
  const int bh = blockIdx.y;
  const int h = bh & 15, b = bh >> 4;
  if (tile * 64 >= kept[b]) return;
  const int tid = threadIdx.x;
  __shared__ __attribute__((aligned(16))) u16 Vl[64 * 64];
#pragma unroll
  for (int i = 0; i < 2; ++i) {
    int chunk = i * 256 + tid;           // 512: slot(64) x seg(8)
    int slot = chunk >> 3, seg = chunk & 7;
    int tok = karr[b * 512 + tile * 64 + slot];
    bf16x8 v;
#pragma unroll
    for (int p = 0; p < 8; ++p) v[p] = 0;
    if (tok != 0xFFFF)
      v = *(const bf16x8*)(Pv + ((size_t)b * 500 + tok) * 1024 + h * 64 + seg * 8);
    *(bf16x8*)&Vl[slot * 64 + seg * 8] = v;
  }
  __syncthreads();
  u16* out = Vtg + ((size_t)bh * 8 + tile) * 4096;
#pragma unroll
  for (int i = 0; i < 2; ++i) {
    int chunk = i * 256 + tid;           // d(64) x c16(8)
    int d = chunk >> 3, c16 = chunk & 7;
    int k0 = ((c16 * 16) ^ ((d & 7) << 4)) >> 1;
    bf16x8 v;
#pragma unroll
    for (int p = 0; p < 8; ++p) v[p] = (short)Vl[(k0 + p) * 64 + d];
    *(bf16x8*)(out + chunk * 8) = v;
  }
}

// ---------------- flash attention: compressed k, swapped QK^T, in-reg softmax ----------------
__global__ __launch_bounds__(512) void attn_kernel(const u16* __restrict__ Qr,
                                                   const u16* __restrict__ Ktg,
                                                   const u16* __restrict__ Vtg,
                                                   const float* __restrict__ rel_emb,
                                                   const u16* __restrict__ karr,
                                                   const int* __restrict__ kept,
                                                   u16* __restrict__ AO) {
  const int bid = blockIdx.x;
  const int bh = ((bid >> 5) << 3) | (bid & 7);
  const int qb = (bid >> 3) & 3;
  const int h = bh & 15, b = bh >> 4;
  const int q0 = qb * 128;
  const int tid = threadIdx.x;
  const int wave = tid >> 6;
  const int fr = tid & 15, fo = (tid >> 4) & 3;

  __shared__ __attribute__((aligned(16))) u16 Ks[2][4096];
  __shared__ __attribute__((aligned(16))) u16 Vs[2][4096];
  __shared__ __attribute__((aligned(16))) u16 Pl[8][1024];
  __shared__ float rel2[640];
  __shared__ u16 okk[512];

  const int nk = kept[b];
  const int nt = (nk + 63) >> 6;
  const float LOG2E = 1.44269504f;
  for (int i = tid; i < 640; i += 512) {
    int g = min(max(q0 - 12 + i, 0), 998);
    rel2[i] = rel_emb[g * 16 + h] * LOG2E;
  }
  okk[tid] = karr[b * 512 + tid];

  const int qloc = wave * 16 + fr;
  const int qg = q0 + qloc;
  const bool qok = (qg < 500);
  const u16* Qb = Qr + ((size_t)bh * 500 + min(qg, 499)) * 64;
  bf16x8 qf0 = *(const bf16x8*)(Qb + fo * 8);
  bf16x8 qf1 = *(const bf16x8*)(Qb + 32 + fo * 8);

  f32x4 o[4];
#pragma unroll
  for (int nf = 0; nf < 4; ++nf)
#pragma unroll
    for (int j = 0; j < 4; ++j) o[nf][j] = 0.f;
  float mrun = -1e30f, lrun = 0.f;

  const u16* Kb = Ktg + (size_t)bh * 32768;
  const u16* Vb = Vtg + (size_t)bh * 32768;
  const int sw = (fr & 7) << 4;
  const float SC = 0.18033688f;          // 0.125 * log2(e)

  if (nt > 0) {
    async16(&Ks[0][tid * 8], Kb + tid * 8);
    async16(&Vs[0][tid * 8], Vb + tid * 8);
  }
  __syncthreads();

  for (int t = 0; t < nt; ++t) {
    const int cur = t & 1;
    if (t + 1 < nt) {
      async16(&Ks[cur ^ 1][tid * 8], Kb + (t + 1) * 4096 + tid * 8);
      async16(&Vs[cur ^ 1][tid * 8], Vb + (t + 1) * 4096 + tid * 8);
    }
    const char* Kt = (const char*)(cur ? &Ks[1][0] : &Ks[0][0]);
    const char* Vt = (const char*)(cur ? &Vs[1][0] : &Vs[0][0]);

    f32x4 sacc[4];
    __builtin_amdgcn_s_setprio(1);
#pragma unroll
    for (int nf = 0; nf < 4; ++nf) {
#pragma unroll
      for (int jj = 0; jj < 4; ++jj) sacc[nf][jj] = 0.f;
      int rb = (nf * 16 + fr) * 128;
      bf16x8 kb0 = *(const bf16x8*)(Kt + rb + ((fo * 16) ^ sw));
      bf16x8 kb1 = *(const bf16x8*)(Kt + rb + ((64 + fo * 16) ^ sw));
      sacc[nf] = __builtin_amdgcn_mfma_f32_16x16x32_bf16(kb0, qf0, sacc[nf], 0, 0, 0);
      sacc[nf] = __builtin_amdgcn_mfma_f32_16x16x32_bf16(kb1, qf1, sacc[nf], 0, 0, 0);
    }
    __builtin_amdgcn_s_setprio(0);

    float p2[4][4];
    float pmax = -1e30f;
#pragma unroll
    for (int nf = 0; nf < 4; ++nf) {
#pragma unroll
      for (int r = 0; r < 4; ++r) {
        int slot = t * 64 + nf * 16 + fo * 4 + r;
        int ok = okk[slot];
        float rv = rel2[min(max(qloc - ok + 511, 0), 639)];
        bool valid = (ok != 0xFFFF) && qok;
        float s2 = valid ? fmaf(sacc[nf][r], SC, rv) : -1e30f;
        p2[nf][r] = s2;
        pmax = fmaxf(pmax, s2);
      }
    }
    pmax = fmaxf(pmax, __shfl_xor(pmax, 16, 64));
    pmax = fmaxf(pmax, __shfl_xor(pmax, 32, 64));

    if (!__all(pmax <= mrun + 8.0f)) {   // defer-max (T13)
      float mnew = fmaxf(mrun, pmax);
      float scl = EXP2(mrun - mnew);
      lrun *= scl;
#pragma unroll
      for (int nf = 0; nf < 4; ++nf)
#pragma unroll
        for (int r = 0; r < 4; ++r) o[nf][r] *= scl;
      mrun = mnew;
    }

    float lsum = 0.f;
#pragma unroll
    for (int nf = 0; nf < 4; ++nf) {
      float e0 = EXP2(p2[nf][0] - mrun);
      float e1 = EXP2(p2[nf][1] - mrun);
      float e2 = EXP2(p2[nf][2] - mrun);
      float e3 = EXP2(p2[nf][3] - mrun);
      lsum += (e0 + e1) + (e2 + e3);
      uint2 w; w.x = packbf(e0, e1); w.y = packbf(e2, e3);
      *(uint2*)((char*)&Pl[wave][0] + fr * 128 + ((nf * 32 + fo * 8) ^ sw)) = w;
    }
    lsum += __shfl_xor(lsum, 16, 64);
    lsum += __shfl_xor(lsum, 32, 64);
    lrun += lsum;

    bf16x8 pa0 = *(const bf16x8*)((char*)&Pl[wave][0] + fr * 128 + ((fo * 16) ^ sw));
    bf16x8 pa1 = *(const bf16x8*)((char*)&Pl[wave][0] + fr * 128 + ((64 + fo * 16) ^ sw));
    __builtin_amdgcn_s_setprio(1);
#pragma unroll
    for (int nf = 0; nf < 4; ++nf) {
      int rb = (nf * 16 + fr) * 128;
      bf16x8 vb0 = *(const bf16x8*)(Vt + rb + ((fo * 16) ^ sw));
      bf16x8 vb1 = *(const bf16x8*)(Vt + rb + ((64 + fo * 16) ^ sw));
      o[nf] = __builtin_amdgcn_mfma_f32_16x16x32_bf16(vb0, pa0, o[nf], 0, 0, 0);
      o[nf] = __builtin_amdgcn_mfma_f32_16x16x32_bf16(vb1, pa1, o[nf], 0, 0, 0);
    }
    __builtin_amdgcn_s_setprio(0);
    __syncthreads();
  }

  float inv = (lrun > 0.f) ? 1.f / lrun : 0.f;
#pragma unroll
  for (int nf = 0; nf < 4; ++nf) {
    float v0 = fminf(fmaxf(o[nf][0] * inv, -30.f), 30.f);
    float v1 = fminf(fmaxf(o[nf][1] * inv, -30.f), 30.f);
    float v2 = fminf(fmaxf(o[nf][2] * inv, -30.f), 30.f);
    float v3 = fminf(fmaxf(o[nf][3] * inv, -30.f), 30.f);
    uint2 w; w.x = packbf(v0, v1); w.y = packbf(v2, v3);
    *(uint2*)((char*)&Pl[wave][0] + fr * 128 + ((nf * 32 + fo * 8) ^ sw)) = w;
  }
  {
    int lane = tid & 63;
    int ro = lane >> 2, c = lane & 3;
    int swr = (ro & 7) << 4;
    const char* Pw = (const char*)&Pl[wave][0];
    bf16x8 v0 = *(const bf16x8*)(Pw + ro * 128 + ((c * 32) ^ swr));
    bf16x8 v1 = *(const bf16x8*)(Pw + ro * 128 + ((c * 32 + 16) ^ swr));
    int token = q0 + wave * 16 + ro;
    if (token < 500) {
      u16* dst = AO + (size_t)(b * 500 + token) * 1024 + h * 64 + c * 16;
      *(bf16x8*)dst = v0;
      *(bf16x8*)(dst + 8) = v1;
    }
  }
}

// ---------------- launch ----------------
extern "C" void kernel_launch(void* const* d_in, const int* in_sizes, int n_in,
                              void* d_out, int out_size, void* d_ws, size_t ws_size,
                              hipStream_t stream) {
  const float* query = (const float*)d_in[0];
  const float* key_  = (const float*)d_in[1];
  const float* value = (const float*)d_in[2];
  const void*  mask  = d_in[3];
  const float* Wq = (const float*)d_in[4];
  const float* bq = (const float*)d_in[5];
  const float* Wk = (const float*)d_in[6];
  const float* bk = (const float*)d_in[7];
  const float* Wv = (const float*)d_in[8];
  const float* bv = (const float*)d_in[9];
  const float* Wo = (const float*)d_in[10];
  const float* bo = (const float*)d_in[11];
  const float* rel = (const float*)d_in[12];

  // ws map: Wb 8.39MB | 4 slots x 32MiB | misc ~0.26MB
  // slot liveness: A: Xq->Pk->Vtg | B: Xk->Qro | C: Xv->Pq->Ktg | D: Pv->AO
  char* ws = (char*)d_ws;
  const size_t SLOT = 33554432;
  u16* Wb = (u16*)ws;
  char* Aq = ws + 8388608;
  char* Bq = Aq + SLOT;
  char* Cq = Bq + SLOT;
  char* Dq = Cq + SLOT;
  char* MISC = Dq + SLOT;
  u8*  maskb = (u8*)MISC;
  u16* karr  = (u16*)(MISC + 65536);
  int* kept  = (int*)(MISC + 131072);
  float* tab = (float*)(MISC + 131584);

  mask_prep<<<1, 256, 0, stream>>>(mask, maskb);
  build_gather<<<32, 512, 0, stream>>>(maskb, karr, kept);
  rope_table<<<63, 256, 0, stream>>>(tab);

  cvt_f32_bf16<<<512, 256, 0, stream>>>(Wq, Wb + 0 * 1048576, 262144);
  cvt_f32_bf16<<<512, 256, 0, stream>>>(Wk, Wb + 1 * 1048576, 262144);
  cvt_f32_bf16<<<512, 256, 0, stream>>>(Wv, Wb + 2 * 1048576, 262144);
  cvt_f32_bf16<<<512, 256, 0, stream>>>(Wo, Wb + 3 * 1048576, 262144);
  cvt_f32_bf16<<<2048, 256, 0, stream>>>(query, (u16*)Aq, 4096000);
  cvt_f32_bf16<<<2048, 256, 0, stream>>>(key_,  (u16*)Bq, 4096000);
  cvt_f32_bf16<<<2048, 256, 0, stream>>>(value, (u16*)Cq, 4096000);

  gemm_bt<true><<<252, 512, 0, stream>>>((u16*)Cq, Wb + 2 * 1048576, bv, Dq, 16000);  // Pv=D
  gemm_bt<true><<<252, 512, 0, stream>>>((u16*)Aq, Wb + 0 * 1048576, bq, Cq, 16000);  // Pq=C
  gemm_bt<true><<<252, 512, 0, stream>>>((u16*)Bq, Wb + 1 * 1048576, bk, Aq, 16000);  // Pk=A

  rope_q<<<32000, 256, 0, stream>>>((u16*)Cq, tab, (u16*)Bq);                   // Qro=B
  gather_k<<<dim3(8, 512), 256, 0, stream>>>((u16*)Aq, tab, karr, kept, (u16*)Cq);  // Ktg=C
  gather_v<<<dim3(8, 512), 256, 0, stream>>>((u16*)Dq, karr, kept, (u16*)Aq);       // Vtg=A

  attn_kernel<<<2048, 512, 0, stream>>>((u16*)Bq, (u16*)Cq, (u16*)Aq, rel,
                                        karr, kept, (u16*)Dq);                  // AO=D

  gemm_bt<false><<<252, 512, 0, stream>>>((u16*)Dq, Wb + 3 * 1048576, bo, (float*)d_out, 16000);
}

// Round 10
// 358.422 us; speedup vs baseline: 1.2883x; 1.0673x over previous
//
#include <hip/hip_runtime.h>
#include <math.h>

// FlashMultiHeadAttention: B=32 S=500 H=1024 NH=16 HD=64, rope + rel-pos-bias + key-pad mask.
// Pipeline: [mask->bytes] [gather-list scan] [rope table] [f32->bf16 cvt]
//           [QKV proj GEMM 256x256 fine-phase; Q-gemm fuses rope+transpose in epilogue]
//           [rope+gather+swizzle K tiles] [gather+transpose+swizzle V tiles]
//           [flash attn: masked-k compressed, swapped QK^T, in-reg softmax] [out proj GEMM]

typedef unsigned short u16;
typedef unsigned int   u32;
typedef unsigned char  u8;
using bf16x8 = __attribute__((ext_vector_type(8))) short;
using f32x4  = __attribute__((ext_vector_type(4))) float;
using f32x2  = __attribute__((ext_vector_type(2))) float;
using u16x4  = __attribute__((ext_vector_type(4))) unsigned short;

#define DEV __device__ __forceinline__

#if __has_builtin(__builtin_amdgcn_exp2f)
#define EXP2(x) __builtin_amdgcn_exp2f(x)
#else
#define EXP2(x) exp2f(x)
#endif

DEV u16 f2bf(float f) {                 // RNE f32 -> bf16
  union { float f; u32 u; } c; c.f = f;
  u32 u = c.u;
  return (u16)((u + 0x7FFFu + ((u >> 16) & 1u)) >> 16);
}
DEV float bf2f(u16 h) {
  union { u32 u; float f; } c; c.u = ((u32)h) << 16;
  return c.f;
}
DEV u32 cvtpk(float a, float b) {       // packed pair via HW cvt (T12)
  u32 r;
  asm("v_cvt_pk_bf16_f32 %0, %1, %2" : "=v"(r) : "v"(a), "v"(b));
  return r;
}

// async global->LDS, 16B/lane; LDS dest = wave-uniform base + lane*16 (linear).
DEV void async16(void* l, const void* g) {
  __builtin_amdgcn_global_load_lds(
      (__attribute__((address_space(1))) unsigned int*)g,
      (__attribute__((address_space(3))) unsigned int*)l, 16, 0, 0);
}

// ---------------- mask prep: detect bool storage (i32/f32/u8), emit bytes ----------------
__global__ __launch_bounds__(256) void mask_prep(const void* __restrict__ mraw,
                                                 u8* __restrict__ maskb) {
  __shared__ int bad_i32, bad_f32;
  if (threadIdx.x == 0) { bad_i32 = 0; bad_f32 = 0; }
  __syncthreads();
  const u32* w = (const u32*)mraw;
  int li = 0, lf = 0;
  for (int g = threadIdx.x; g < 4000; g += 256) {
    u32 v = w[g];
    li |= !(v == 0u || v == 1u);
    lf |= !(v == 0u || v == 0x3F800000u);
  }
  if (li) atomicOr(&bad_i32, 1);
  if (lf) atomicOr(&bad_f32, 1);
  __syncthreads();
  int mode = (!bad_i32) ? 0 : ((!bad_f32) ? 1 : 2);   // 0=int32, 1=float32, 2=uint8
  for (int i = threadIdx.x; i < 16000; i += 256) {
    int v;
    if (mode == 0)      v = ((const int*)mraw)[i] != 0;
    else if (mode == 1) v = (((const float*)mraw)[i] != 0.0f);
    else                v = ((const u8*)mraw)[i] != 0;
    maskb[i] = (u8)v;
  }
}

// ---------------- per-batch gather list: karr[b][512] = kept token or 0xFFFF ----------------
__global__ __launch_bounds__(512) void build_gather(const u8* __restrict__ maskb,
                                                    u16* __restrict__ karr,
                                                    int* __restrict__ kept) {
  const int b = blockIdx.x;
  const int t = threadIdx.x;
  const int lane = t & 63, wave = t >> 6;
  __shared__ int wbase[8];
  __shared__ int wpop[8];
  int v = (t < 500) ? (int)maskb[b * 500 + t] : 0;
  unsigned long long bal = __ballot(v != 0);
  karr[b * 512 + t] = 0xFFFF;
  if (lane == 0) wpop[wave] = __popcll(bal);
  __syncthreads();
  if (t == 0) {
    int s = 0;
    for (int w = 0; w < 8; ++w) { wbase[w] = s; s += wpop[w]; }
    kept[b] = s;
  }
  __syncthreads();
  if (v) {
    int rank = wbase[wave] + __popcll(bal & ((1ull << lane) - 1ull));
    karr[b * 512 + rank] = (u16)t;
  }
}

// ---------------- rope cos/sin table: tab[(s*32+j)*2] = cos, +1 = sin ----------------
__global__ __launch_bounds__(256) void rope_table(float* __restrict__ tab) {
  int idx = blockIdx.x * 256 + threadIdx.x;
  if (idx >= 16000) return;
  int s = idx >> 5, j = idx & 31;
  float ang = (float)s * exp2f(-(float)j * 0.41524100f);  // 10000^(-j/32)
  float sn, cs;
  sincosf(ang, &sn, &cs);
  tab[idx * 2] = cs;
  tab[idx * 2 + 1] = sn;
}

// ---------------- f32 -> bf16 convert (vectorized) ----------------
__global__ __launch_bounds__(256) void cvt_f32_bf16(const float* __restrict__ src,
                                                    u16* __restrict__ dst, int n4) {
  int i = blockIdx.x * 256 + threadIdx.x;
  int stride = gridDim.x * 256;
  for (; i < n4; i += stride) {
    f32x4 f = *(const f32x4*)(src + (size_t)i * 4);
    u16x4 o;
    o[0] = f2bf(f[0]); o[1] = f2bf(f[1]); o[2] = f2bf(f[2]); o[3] = f2bf(f[3]);
    *(u16x4*)(dst + (size_t)i * 4) = o;
  }
}

// ---------------- GEMM: C[m][n] = sum_k A[m][k]*Bw[n][k] + bias[n] ----------------
// 256x256 tile, BK=32, 512 thr / 8 waves (2x4), per-wave 128x64; XOR-swizzled LDS;
// fine-phase counted-vmcnt schedule (round-8/9, proven).
// MODE: 0 = f32 out [m][1024]; 1 = bf16 out [m][1024]; 2 = bf16 + rope + transpose
//       to [b][h][s][64] (Q projection; wave's 64-col strip == one head).
template <int MODE>
__global__ __launch_bounds__(512, 2) void gemm_bt(const u16* __restrict__ A,
                                                  const u16* __restrict__ Bw,
                                                  const float* __restrict__ bias,
                                                  void* __restrict__ Cout, int M,
                                                  const float* __restrict__ tabg) {
  const int bid = blockIdx.x;
  const int xcd = bid & 7, idx = bid >> 3;            // dispatch round-robins XCDs
  const int swz = (xcd < 4 ? xcd * 32 : 128 + (xcd - 4) * 31) + idx;  // 252 = 4*32+4*31
  const int m0 = (swz >> 2) * 256;                    // consecutive swz share A panel
  const int n0 = (swz & 3) * 256;
  const int tid = threadIdx.x;
  const int wave = tid >> 6;
  const int wr = wave >> 2, wc = wave & 3;
  const int fr = tid & 15, fo = (tid >> 4) & 3;
  const int fr2 = fr >> 1;
  const int aslot = ((4 * (fr & 1) + fo) ^ fr2) * 8;  // u16 offset within 64-u16 LDS row

  const int TILE = 256 * 32;                          // u16 elems per buffer (16KB)
  __shared__ __attribute__((aligned(16))) u16 As[3 * 256 * 32];   // 48KB
  __shared__ __attribute__((aligned(16))) u16 Bs[3 * 256 * 32];   // 48KB

  f32x4 acc[8][4];
#pragma unroll
  for (int mi = 0; mi < 8; ++mi)
#pragma unroll
    for (int ni = 0; ni < 4; ++ni)
#pragma unroll
      for (int j = 0; j < 4; ++j) acc[mi][ni][j] = 0.f;

  auto STAGE_A = [&](int kt2, u16* sA) {
#pragma unroll
    for (int i = 0; i < 2; ++i) {
      int c = i * 512 + tid;
      int r = c >> 3, v = (c & 7) ^ (r & 7);
      int ar = min(m0 + 2 * r + (v >> 2), M - 1);
      async16(&sA[c * 8], A + (size_t)ar * 1024 + kt2 * 32 + (v & 3) * 8);
    }
  };
  auto STAGE_B = [&](int kt2, u16* sB) {
#pragma unroll
    for (int i = 0; i < 2; ++i) {
      int c = i * 512 + tid;
      int r = c >> 3, v = (c & 7) ^ (r & 7);
      int nr = n0 + 2 * r + (v >> 2);
      async16(&sB[c * 8], Bw + (size_t)nr * 1024 + kt2 * 32 + (v & 3) * 8);
    }
  };

  u16 *a0 = &As[0], *a1 = &As[TILE], *a2 = &As[2 * TILE];
  u16 *b0 = &Bs[0], *b1 = &Bs[TILE], *b2 = &Bs[2 * TILE];
  STAGE_A(0, a0); STAGE_B(0, b0);                     // 4 vmem instrs (tile 0)
  STAGE_A(1, a1); STAGE_B(1, b1);                     // 4 more (tile 1)
  asm volatile("s_waitcnt vmcnt(4)" ::: "memory");    // tile 0 landed; tile 1 in flight
  __builtin_amdgcn_sched_barrier(0);
  __builtin_amdgcn_s_barrier();

  for (int kt = 0; kt < 32; ++kt) {
    const bool st = (kt + 2 < 32);
    // ---- phase 0: frags m0-3 + all b; stage A of kt+2 ----
    bf16x8 a[8], b[4];
#pragma unroll
    for (int mi = 0; mi < 4; ++mi)
      a[mi] = *(const bf16x8*)&a0[(wr * 64 + mi * 8 + fr2) * 64 + aslot];
#pragma unroll
    for (int ni = 0; ni < 4; ++ni)
      b[ni] = *(const bf16x8*)&b0[(wc * 32 + ni * 8 + fr2) * 64 + aslot];
    if (st) STAGE_A(kt + 2, a2);
    __builtin_amdgcn_s_barrier();
    asm volatile("s_waitcnt lgkmcnt(0)" ::: "memory");
    __builtin_amdgcn_sched_barrier(0);
    __builtin_amdgcn_s_setprio(1);
#pragma unroll
    for (int mi = 0; mi < 4; ++mi)
#pragma unroll
      for (int ni = 0; ni < 4; ++ni)
        acc[mi][ni] = __builtin_amdgcn_mfma_f32_16x16x32_bf16(a[mi], b[ni], acc[mi][ni], 0, 0, 0);
    __builtin_amdgcn_s_setprio(0);
    __builtin_amdgcn_s_barrier();

    // ---- phase 1: frags m4-7; stage B of kt+2 ----
#pragma unroll
    for (int mi = 4; mi < 8; ++mi)
      a[mi] = *(const bf16x8*)&a0[(wr * 64 + mi * 8 + fr2) * 64 + aslot];
    if (st) STAGE_B(kt + 2, b2);
    __builtin_amdgcn_s_barrier();
    asm volatile("s_waitcnt lgkmcnt(0)" ::: "memory");
    __builtin_amdgcn_sched_barrier(0);
    __builtin_amdgcn_s_setprio(1);
#pragma unroll
    for (int mi = 4; mi < 8; ++mi)
#pragma unroll
      for (int ni = 0; ni < 4; ++ni)
        acc[mi][ni] = __builtin_amdgcn_mfma_f32_16x16x32_bf16(a[mi], b[ni], acc[mi][ni], 0, 0, 0);
    __builtin_amdgcn_s_setprio(0);
    if (kt < 31) {                                    // validate tile kt+1 before next iter
      if (st) asm volatile("s_waitcnt vmcnt(4)" ::: "memory");
      else    asm volatile("s_waitcnt vmcnt(0)" ::: "memory");
      __builtin_amdgcn_sched_barrier(0);
    }
    __builtin_amdgcn_s_barrier();                     // gates reuse of a0/b0 by next STAGE

    u16* t;
    t = a0; a0 = a1; a1 = a2; a2 = t;
    t = b0; b0 = b1; b1 = b2; b2 = t;
  }

  // ---- epilogue ----
  __syncthreads();                                    // all waves done with LDS tiles
  if (MODE == 2) {
    // rope + transpose: wave strip = head h; bounce f32, rope from tab, write [bh][s][d]
    float* fw = (float*)&As[0] + wave * 1024;         // 16 rows x 64 f32 = 4KB per wave
    const int hh = (n0 >> 6) + wc;
    const int lane = tid & 63;
    const int row = lane >> 2;                        // 0..15
    const int jb = (lane & 3) * 8;                    // j block base
    float bvv[4];
#pragma unroll
    for (int ni = 0; ni < 4; ++ni) bvv[ni] = bias[n0 + wc * 64 + ni * 16 + fr];
#pragma unroll
    for (int mi = 0; mi < 8; ++mi) {
#pragma unroll
      for (int ni = 0; ni < 4; ++ni)
#pragma unroll
        for (int r = 0; r < 4; ++r)
          fw[(fo * 4 + r) * 64 + ni * 16 + fr] = acc[mi][ni][r] + bvv[ni];
      // within-wave LDS RAW: compiler inserts lgkmcnt
      int m = m0 + wr * 128 + mi * 16 + row;
      if (m < M) {
        int bb = (u32)m / 500u;
        int ss = m - bb * 500;
        u16* dst = (u16*)Cout + (((size_t)(bb * 16 + hh)) * 500 + ss) * 64;
        bf16x8 va, vb;
#pragma unroll
        for (int p = 0; p < 8; ++p) {
          int j = jb + p;
          float x0 = fw[row * 64 + j];
          float x1 = fw[row * 64 + 32 + j];
          float xe = fw[row * 64 + 2 * j];
          float xo = fw[row * 64 + 2 * j + 1];
          f32x2 cn = *(const f32x2*)(tabg + (ss * 32 + j) * 2);
          va[p] = (short)f2bf(x0 * cn[0] - xo * cn[1]);
          vb[p] = (short)f2bf(x1 * cn[0] + xe * cn[1]);
        }
        *(bf16x8*)(dst + jb) = va;
        *(bf16x8*)(dst + 32 + jb) = vb;
      }
      __builtin_amdgcn_s_barrier();                   // waves share As region pacing (uniform)
    }
  } else if (MODE == 1) {
    u16* bw = (u16*)&As[0] + wave * 2048;             // 4KB region per wave
#pragma unroll
    for (int mi = 0; mi < 8; ++mi) {
#pragma unroll
      for (int ni = 0; ni < 4; ++ni) {
        float bv = bias[n0 + wc * 64 + ni * 16 + fr];
#pragma unroll
        for (int r = 0; r < 4; ++r)
          bw[(fo * 4 + r) * 64 + ni * 16 + fr] = f2bf(acc[mi][ni][r] + bv);
      }
      int lane = tid & 63;
      int ro = lane >> 2, ch = lane & 3;
      int m = m0 + wr * 128 + mi * 16 + ro;
      bf16x8 v0 = *(const bf16x8*)&bw[ro * 64 + ch * 16];
      bf16x8 v1 = *(const bf16x8*)&bw[ro * 64 + ch * 16 + 8];
      if (m < M) {
        u16* dst = (u16*)Cout + (size_t)m * 1024 + n0 + wc * 64 + ch * 16;
        *(bf16x8*)dst = v0;
        *(bf16x8*)(dst + 8) = v1;
      }
    }
  } else {
    float* fw = (float*)&As[0] + wave * 1024;         // 4KB region per wave
#pragma unroll
    for (int mi = 0; mi < 8; ++mi) {
#pragma unroll
      for (int ni = 0; ni < 4; ++ni) {
        float bv = bias[n0 + wc * 64 + ni * 16 + fr];
#pragma unroll
        for (int r = 0; r < 4; ++r)
          fw[(fo * 4 + r) * 64 + ni * 16 + fr] = acc[mi][ni][r] + bv;
      }
      int lane = tid & 63;
      int ro = lane >> 2, ch = lane & 3;
      int m = m0 + wr * 128 + mi * 16 + ro;
      f32x4 v0 = *(const f32x4*)&fw[ro * 64 + ch * 16];
      f32x4 v1 = *(const f32x4*)&fw[ro * 64 + ch * 16 + 4];
      f32x4 v2 = *(const f32x4*)&fw[ro * 64 + ch * 16 + 8];
      f32x4 v3 = *(const f32x4*)&fw[ro * 64 + ch * 16 + 12];
      if (m < M) {
        float* dst = (float*)Cout + (size_t)m * 1024 + n0 + wc * 64 + ch * 16;
        *(f32x4*)dst = v0;
        *(f32x4*)(dst + 4) = v1;
        *(f32x4*)(dst + 8) = v2;
        *(f32x4*)(dst + 12) = v3;
      }
    }
  }
}

// ---------------- K: rope + gather kept tokens -> pre-swizzled tiles [bh][tile][64][128B] ------
__global__ __launch_bounds__(256) void gather_k(const u16* __restrict__ Pk,
                                                const float* __restrict__ tab,
                                                const u16* __restrict__ karr,
                                                const int* __restrict__ kept,
                                                u16* __restrict__ Ktg) {
  const int tile = blockIdx.x;
  const int bh = blockIdx.y;
  const int h = bh & 15, b = bh >> 4;
  if (tile * 64 >= kept[b]) return;
  char* out = (char*)(Ktg + ((size_t)bh * 8 + tile) * 4096);
  const int tid = threadIdx.x;
#pragma unroll
  for (int i = 0; i < 8; ++i) {
    int item = i * 256 + tid;            // 2048 = 64 rows * 32 j
    int row = item >> 5, j = item & 31;
    int tok = karr[b * 512 + tile * 64 + row];
    int sw = (row & 7) << 4;
    u16 o0 = 0, o1 = 0;
    if (tok != 0xFFFF) {
      const u16* src = Pk + ((size_t)b * 500 + tok) * 1024 + h * 64;
      float x0 = bf2f(src[j]);
      float x1 = bf2f(src[32 + j]);
      float xe = bf2f(src[2 * j]);
      float xo = bf2f(src[2 * j + 1]);
      f32x2 cn = *(const f32x2*)(tab + (tok * 32 + j) * 2);
      o0 = f2bf(x0 * cn[0] - xo * cn[1]);
      o1 = f2bf(x1 * cn[0] + xe * cn[1]);
    }
    *(u16*)(out + row * 128 + ((2 * j) ^ sw)) = o0;
    *(u16*)(out + row * 128 + ((64 + 2 * j) ^ sw)) = o1;
  }
}

// ---------------- V: gather + transpose -> pre-swizzled V^T tiles [bh][tile][64 d][128B] ------
__global__ __launch_bounds__(256) void gather_v(const u16* __restrict__ Pv,
                                                const u16* __restrict__ karr,
                                                const int* __restrict__ kept,
                                                u16* __restrict__ Vtg) {
  const int tile = blockIdx.x;
  const int bh = blockIdx.y;
  const int h = bh & 15, b = bh >> 4;
  if (tile * 64 >= kept[b]) return;
  const int tid = threadIdx.x;
  __shared__ __attribute__((aligned(16))) u16 Vl[64 * 64];
#pragma unroll
  for (int i = 0; i < 2; ++i) {
    int chunk = i * 256 + tid;           // 512: slot(64) x seg(8)
    int slot = chunk >> 3, seg = chunk & 7;
    int tok = karr[b * 512 + tile * 64 + slot];
    bf16x8 v;
#pragma unroll
    for (int p = 0; p < 8; ++p) v[p] = 0;
    if (tok != 0xFFFF)
      v = *(const bf16x8*)(Pv + ((size_t)b * 500 + tok) * 1024 + h * 64 + seg * 8);
    *(bf16x8*)&Vl[slot * 64 + seg * 8] = v;
  }
  __syncthreads();
  u16* out = Vtg + ((size_t)bh * 8 + tile) * 4096;
#pragma unroll
  for (int i = 0; i < 2; ++i) {
    int chunk = i * 256 + tid;           // d(64) x c16(8)
    int d = chunk >> 3, c16 = chunk & 7;
    int k0 = ((c16 * 16) ^ ((d & 7) << 4)) >> 1;
    bf16x8 v;
#pragma unroll
    for (int p = 0; p < 8; ++p) v[p] = (short)Vl[(k0 + p) * 64 + d];
    *(bf16x8*)(out + chunk * 8) = v;
  }
}

// ---------------- flash attention: compressed k, swapped QK^T, in-reg softmax ----------------
__global__ __launch_bounds__(512) void attn_kernel(const u16* __restrict__ Qr,
                                                   const u16* __restrict__ Ktg,
                                                   const u16* __restrict__ Vtg,
                                                   const float* __restrict__ rel_emb,
                                                   const u16* __restrict__ karr,
                                                   const int* __restrict__ kept,
                                                   u16* __restrict__ AO) {
  const int bid = blockIdx.x;
  const int bh = ((bid >> 5) << 3) | (bid & 7);
  const int qb = (bid >> 3) & 3;
  const int h = bh & 15, b = bh >> 4;
  const int q0 = qb * 128;
  const int tid = threadIdx.x;
  const int wave = tid >> 6;
  const int fr = tid & 15, fo = (tid >> 4) & 3;

  __shared__ __attribute__((aligned(16))) u16 Ks[2][4096];
  __shared__ __attribute__((aligned(16))) u16 Vs[2][4096];
  __shared__ __attribute__((aligned(16))) u16 Pl[8][1024];
  __shared__ float rel2[640];
  __shared__ u16 okk[512];

  const int nt = (kept[b] + 63) >> 6;
  const float LOG2E = 1.44269504f;
  for (int i = tid; i < 640; i += 512) {
    int g = min(max(q0 - 12 + i, 0), 998);
    rel2[i] = (i == 0) ? -1e30f : rel_emb[g * 16 + h] * LOG2E;   // rel2[0] = pad sentinel
  }
  okk[tid] = karr[b * 512 + tid];

  const int qloc = wave * 16 + fr;
  const int qc = qloc + 511;             // pad slot (ok=0xFFFF) -> idx<0 -> clamp 0 -> -1e30
  const u16* Qb = Qr + ((size_t)bh * 500 + min(q0 + qloc, 499)) * 64;
  bf16x8 qf0 = *(const bf16x8*)(Qb + fo * 8);
  bf16x8 qf1 = *(const bf16x8*)(Qb + 32 + fo * 8);

  f32x4 o[4];
#pragma unroll
  for (int nf = 0; nf < 4; ++nf)
#pragma unroll
    for (int j = 0; j < 4; ++j) o[nf][j] = 0.f;
  float mrun = -1e30f, lrun = 0.f;

  const u16* Kb = Ktg + (size_t)bh * 32768;
  const u16* Vb = Vtg + (size_t)bh * 32768;
  const int sw = (fr & 7) << 4;
  const float SC = 0.18033688f;          // 0.125 * log2(e)

  if (nt > 0) {
    async16(&Ks[0][tid * 8], Kb + tid * 8);
    async16(&Vs[0][tid * 8], Vb + tid * 8);
  }
  __syncthreads();

  for (int t = 0; t < nt; ++t) {
    const int cur = t & 1;
    if (t + 1 < nt) {
      async16(&Ks[cur ^ 1][tid * 8], Kb + (t + 1) * 4096 + tid * 8);
      async16(&Vs[cur ^ 1][tid * 8], Vb + (t + 1) * 4096 + tid * 8);
    }
    const char* Kt = (const char*)(cur ? &Ks[1][0] : &Ks[0][0]);
    const char* Vt = (const char*)(cur ? &Vs[1][0] : &Vs[0][0]);

    f32x4 sacc[4];
    __builtin_amdgcn_s_setprio(1);
#pragma unroll
    for (int nf = 0; nf < 4; ++nf) {
#pragma unroll
      for (int jj = 0; jj < 4; ++jj) sacc[nf][jj] = 0.f;
      int rb = (nf * 16 + fr) * 128;
      bf16x8 kb0 = *(const bf16x8*)(Kt + rb + ((fo * 16) ^ sw));
      bf16x8 kb1 = *(const bf16x8*)(Kt + rb + ((64 + fo * 16) ^ sw));
      sacc[nf] = __builtin_amdgcn_mfma_f32_16x16x32_bf16(kb0, qf0, sacc[nf], 0, 0, 0);
      sacc[nf] = __builtin_amdgcn_mfma_f32_16x16x32_bf16(kb1, qf1, sacc[nf], 0, 0, 0);
    }
    __builtin_amdgcn_s_setprio(0);

    // scores: idx = max(qc - ok, 0); pad -> rel2[0] = -1e30 (sacc=0 there)
    float p2[4][4];
    float pmax = -3e30f;
#pragma unroll
    for (int nf = 0; nf < 4; ++nf) {
      u16x4 ok4 = *(const u16x4*)&okk[t * 64 + nf * 16 + fo * 4];
#pragma unroll
      for (int r = 0; r < 4; ++r) {
        int idx2 = max(qc - (int)ok4[r], 0);
        float s2 = fmaf(sacc[nf][r], SC, rel2[idx2]);
        p2[nf][r] = s2;
        pmax = fmaxf(pmax, s2);
      }
    }
    pmax = fmaxf(pmax, __shfl_xor(pmax, 16, 64));
    pmax = fmaxf(pmax, __shfl_xor(pmax, 32, 64));

    if (!__all(pmax <= mrun + 8.0f)) {   // defer-max (T13)
      float mnew = fmaxf(mrun, pmax);
      float scl = EXP2(mrun - mnew);
      lrun *= scl;
#pragma unroll
      for (int nf = 0; nf < 4; ++nf)
#pragma unroll
        for (int r = 0; r < 4; ++r) o[nf][r] *= scl;
      mrun = mnew;
    }

    float lsum = 0.f;
#pragma unroll
    for (int nf = 0; nf < 4; ++nf) {
      float e0 = EXP2(p2[nf][0] - mrun);
      float e1 = EXP2(p2[nf][1] - mrun);
      float e2 = EXP2(p2[nf][2] - mrun);
      float e3 = EXP2(p2[nf][3] - mrun);
      lsum += (e0 + e1) + (e2 + e3);
      uint2 w; w.x = cvtpk(e0, e1); w.y = cvtpk(e2, e3);
      *(uint2*)((char*)&Pl[wave][0] + fr * 128 + ((nf * 32 + fo * 8) ^ sw)) = w;
    }
    lsum += __shfl_xor(lsum, 16, 64);
    lsum += __shfl_xor(lsum, 32, 64);
    lrun += lsum;

    bf16x8 pa0 = *(const bf16x8*)((char*)&Pl[wave][0] + fr * 128 + ((fo * 16) ^ sw));
    bf16x8 pa1 = *(const bf16x8*)((char*)&Pl[wave][0] + fr * 128 + ((64 + fo * 16) ^ sw));
    __builtin_amdgcn_s_setprio(1);
#pragma unroll
    for (int nf = 0; nf < 4; ++nf) {
      int rb = (nf * 16 + fr) * 128;
      bf16x8 vb0 = *(const bf16x8*)(Vt + rb + ((fo * 16) ^ sw));
      bf16x8 vb1 = *(const bf16x8*)(Vt + rb + ((64 + fo * 16) ^ sw));
      o[nf] = __builtin_amdgcn_mfma_f32_16x16x32_bf16(vb0, pa0, o[nf], 0, 0, 0);
      o[nf] = __builtin_amdgcn_mfma_f32_16x16x32_bf16(vb1, pa1, o[nf], 0, 0, 0);
    }
    __builtin_amdgcn_s_setprio(0);
    __syncthreads();
  }

  float inv = (lrun > 0.f) ? 1.f / lrun : 0.f;
#pragma unroll
  for (int nf = 0; nf < 4; ++nf) {
    float v0 = fminf(fmaxf(o[nf][0] * inv, -30.f), 30.f);
    float v1 = fminf(fmaxf(o[nf][1] * inv, -30.f), 30.f);
    float v2 = fminf(fmaxf(o[nf][2] * inv, -30.f), 30.f);
    float v3 = fminf(fmaxf(o[nf][3] * inv, -30.f), 30.f);
    uint2 w; w.x = cvtpk(v0, v1); w.y = cvtpk(v2, v3);
    *(uint2*)((char*)&Pl[wave][0] + fr * 128 + ((nf * 32 + fo * 8) ^ sw)) = w;
  }
  {
    int lane = tid & 63;
    int ro = lane >> 2, c = lane & 3;
    int swr = (ro & 7) << 4;
    const char* Pw = (const char*)&Pl[wave][0];
    bf16x8 v0 = *(const bf16x8*)(Pw + ro * 128 + ((c * 32) ^ swr));
    bf16x8 v1 = *(const bf16x8*)(Pw + ro * 128 + ((c * 32 + 16) ^ swr));
    int token = q0 + wave * 16 + ro;
    if (token < 500) {
      u16* dst = AO + (size_t)(b * 500 + token) * 1024 + h * 64 + c * 16;
      *(bf16x8*)dst = v0;
      *(bf16x8*)(dst + 8) = v1;
    }
  }
}

// ---------------- launch ----------------
extern "C" void kernel_launch(void* const* d_in, const int* in_sizes, int n_in,
                              void* d_out, int out_size, void* d_ws, size_t ws_size,
                              hipStream_t stream) {
  const float* query = (const float*)d_in[0];
  const float* key_  = (const float*)d_in[1];
  const float* value = (const float*)d_in[2];
  const void*  mask  = d_in[3];
  const float* Wq = (const float*)d_in[4];
  const float* bq = (const float*)d_in[5];
  const float* Wk = (const float*)d_in[6];
  const float* bk = (const float*)d_in[7];
  const float* Wv = (const float*)d_in[8];
  const float* bv = (const float*)d_in[9];
  const float* Wo = (const float*)d_in[10];
  const float* bo = (const float*)d_in[11];
  const float* rel = (const float*)d_in[12];

  // ws map: Wb 8.39MB | 4 slots x 32MiB | misc ~0.26MB
  // slot liveness: A: Xq->Pk | B: Xk->Ktg | C: Xv->Qro | D: Pv->AO ; Vtg reuses A
  char* ws = (char*)d_ws;
  const size_t SLOT = 33554432;
  u16* Wb = (u16*)ws;
  char* Aq = ws + 8388608;
  char* Bq = Aq + SLOT;
  char* Cq = Bq + SLOT;
  char* Dq = Cq + SLOT;
  char* MISC = Dq + SLOT;
  u8*  maskb = (u8*)MISC;
  u16* karr  = (u16*)(MISC + 65536);
  int* kept  = (int*)(MISC + 131072);
  float* tab = (float*)(MISC + 131584);

  mask_prep<<<1, 256, 0, stream>>>(mask, maskb);
  build_gather<<<32, 512, 0, stream>>>(maskb, karr, kept);
  rope_table<<<63, 256, 0, stream>>>(tab);

  cvt_f32_bf16<<<512, 256, 0, stream>>>(Wq, Wb + 0 * 1048576, 262144);
  cvt_f32_bf16<<<512, 256, 0, stream>>>(Wk, Wb + 1 * 1048576, 262144);
  cvt_f32_bf16<<<512, 256, 0, stream>>>(Wv, Wb + 2 * 1048576, 262144);
  cvt_f32_bf16<<<512, 256, 0, stream>>>(Wo, Wb + 3 * 1048576, 262144);
  cvt_f32_bf16<<<2048, 256, 0, stream>>>(query, (u16*)Aq, 4096000);
  cvt_f32_bf16<<<2048, 256, 0, stream>>>(key_,  (u16*)Bq, 4096000);
  cvt_f32_bf16<<<2048, 256, 0, stream>>>(value, (u16*)Cq, 4096000);

  gemm_bt<1><<<252, 512, 0, stream>>>((u16*)Cq, Wb + 2 * 1048576, bv, Dq, 16000, tab);  // Pv=D
  gemm_bt<2><<<252, 512, 0, stream>>>((u16*)Aq, Wb + 0 * 1048576, bq, Cq, 16000, tab);  // Qro=C (rope+tr)
  gemm_bt<1><<<252, 512, 0, stream>>>((u16*)Bq, Wb + 1 * 1048576, bk, Aq, 16000, tab);  // Pk=A

  gather_k<<<dim3(8, 512), 256, 0, stream>>>((u16*)Aq, tab, karr, kept, (u16*)Bq);  // Ktg=B
  gather_v<<<dim3(8, 512), 256, 0, stream>>>((u16*)Dq, karr, kept, (u16*)Aq);       // Vtg=A

  attn_kernel<<<2048, 512, 0, stream>>>((u16*)Cq, (u16*)Bq, (u16*)Aq, rel,
                                        karr, kept, (u16*)Dq);                  // AO=D

  gemm_bt<0><<<252, 512, 0, stream>>>((u16*)Dq, Wb + 3 * 1048576, bo, (float*)d_out, 16000, tab);
}